// Round 1
// baseline (5836.511 us; speedup 1.0000x reference)
//
#include <hip/hip_runtime.h>
#include <math.h>

#define NPTS  8192
#define NB    2
#define NTOT  (NPTS*NB)
#define GD    60
#define NCELL (GD*GD*GD)
#define TOTC  (NB*NCELL)
#define HCELL 0.2f
#define INVH  5.0f
#define ORGN  (-6.0f)
#define CAPB  28
#define NN    8192

// ---------------- workspace layout (bytes) ----------------
#define OFF_CNT     ((size_t)0)
#define OFF_OFFS    (OFF_CNT    + (size_t)TOTC*4)
#define OFF_CELLID  (OFF_OFFS   + (size_t)TOTC*4)
#define OFF_RANK    (OFF_CELLID + (size_t)NTOT*4)
#define OFF_SPOS    (OFF_RANK   + (size_t)NTOT*4)          // float4 * NTOT
#define OFF_SIDX    (OFF_SPOS   + (size_t)NTOT*16)
#define OFF_KNN     (OFF_SIDX   + (size_t)NTOT*4)          // int * NTOT*16
#define OFF_SPATIAL (OFF_KNN    + (size_t)NTOT*16*4)       // [B,4,N]
#define OFF_XT      (OFF_SPATIAL+ (size_t)NB*4*NPTS*4)     // [B,N,128]
#define OFF_MD      (OFF_XT     + (size_t)NB*128*NPTS*4)   // [B,128,N]
#define OFF_S1      (OFF_MD     + (size_t)NB*128*NPTS*4)   // [B,32,N]
#define OFF_SF      (OFF_S1     + (size_t)NB*32*NPTS*4)    // [B,64,N]
#define OFF_Y1      (OFF_SF     + (size_t)NB*64*NPTS*4)    // [B,128,N]
#define OFF_Y2      (OFF_Y1     + (size_t)NB*128*NPTS*4)   // [B,128,N]
#define OFF_A1      (OFF_Y2     + (size_t)NB*128*NPTS*4)   // [B,64,N]
#define OFF_SC      (OFF_A1     + (size_t)NB*64*NPTS*4)    // 1088 floats

// Replicate reference arithmetic exactly (no fma contraction): numpy computes
// xx = (x*x + y*y) + z*z ; dist = (xx_n + xx_m) - 2*dot, dot left-to-right.
static __device__ __forceinline__ float sumsq3(float x, float y, float z) {
    return __fadd_rn(__fadd_rn(__fmul_rn(x, x), __fmul_rn(y, y)), __fmul_rn(z, z));
}
static __device__ __forceinline__ float pdist(const float4 q, const float4 p) {
    float dot = __fadd_rn(__fadd_rn(__fmul_rn(q.x, p.x), __fmul_rn(q.y, p.y)), __fmul_rn(q.z, p.z));
    return __fsub_rn(__fadd_rn(q.w, p.w), __fadd_rn(dot, dot));
}

// ---------------- grid build ----------------
__global__ void cell_build(const float* __restrict__ xyz, int* __restrict__ cnt,
                           int* __restrict__ cellid, int* __restrict__ rank) {
    int t = blockIdx.x * 256 + threadIdx.x;
    if (t >= NTOT) return;
    const float* p = xyz + (size_t)t * 3;
    float x = p[0], y = p[1], z = p[2];
    int cx = min(GD - 1, max(0, (int)floorf((x - ORGN) * INVH)));
    int cy = min(GD - 1, max(0, (int)floorf((y - ORGN) * INVH)));
    int cz = min(GD - 1, max(0, (int)floorf((z - ORGN) * INVH)));
    int gcell = (t >> 13) * NCELL + (cz * GD + cy) * GD + cx;
    rank[t] = atomicAdd(&cnt[gcell], 1);
    cellid[t] = gcell;
}

__global__ __launch_bounds__(1024) void prefix_k(const int* __restrict__ cnt, int* __restrict__ offs) {
    __shared__ int ps[1024];
    const int PER = (TOTC + 1023) / 1024;
    int t = threadIdx.x;
    int start = t * PER;
    int s = 0;
    for (int i = 0; i < PER; ++i) { int idx = start + i; if (idx < TOTC) s += cnt[idx]; }
    ps[t] = s;
    __syncthreads();
    for (int d = 1; d < 1024; d <<= 1) {
        int v = 0;
        if (t >= d) v = ps[t - d];
        __syncthreads();
        ps[t] += v;
        __syncthreads();
    }
    int run = (t == 0) ? 0 : ps[t - 1];
    for (int i = 0; i < PER; ++i) {
        int idx = start + i;
        if (idx < TOTC) { offs[idx] = run; run += cnt[idx]; }
    }
}

__global__ void scatter_k(const float* __restrict__ xyz, const int* __restrict__ cellid,
                          const int* __restrict__ rank, const int* __restrict__ offs,
                          float4* __restrict__ spos, int* __restrict__ sidx) {
    int t = blockIdx.x * 256 + threadIdx.x;
    if (t >= NTOT) return;
    const float* p = xyz + (size_t)t * 3;
    float x = p[0], y = p[1], z = p[2];
    int pos = offs[cellid[t]] + rank[t];
    spos[pos] = make_float4(x, y, z, sumsq3(x, y, z));
    sidx[pos] = t & (NPTS - 1);
}

// ---------------- exact KNN (ring expansion over grid) ----------------
__global__ __launch_bounds__(64) void knn_kernel(const float4* __restrict__ spos,
                                                 const int* __restrict__ sidx,
                                                 const int* __restrict__ cnt,
                                                 const int* __restrict__ offs,
                                                 int* __restrict__ knn,
                                                 float* __restrict__ spatial) {
    __shared__ float bd[64][29];   // stride 29: gcd(29,32)=1 -> conflict-light
    __shared__ int   bs[64][29];
    __shared__ int   bo[64][29];
    int t = threadIdx.x;
    int s = blockIdx.x * 64 + t;
    float4 q = spos[s];
    int b  = s >> 13;
    int nq = sidx[s];
    int cxl = min(GD - 1, max(0, (int)floorf((q.x - ORGN) * INVH)));
    int cyl = min(GD - 1, max(0, (int)floorf((q.y - ORGN) * INVH)));
    int czl = min(GD - 1, max(0, (int)floorf((q.z - ORGN) * INVH)));
    const int* cb = cnt  + b * NCELL;
    const int* ob = offs + b * NCELL;

    // shell enumerator: cells with Chebyshev distance exactly R (clamped to grid)
    auto for_shell = [&](int R, auto&& body) {
        for (int dz = -R; dz <= R; ++dz) {
            int zz = czl + dz;
            if ((unsigned)zz >= GD) continue;
            bool ez = (dz == -R) || (dz == R);
            for (int dy = -R; dy <= R; ++dy) {
                int yy = cyl + dy;
                if ((unsigned)yy >= GD) continue;
                int step = (ez || dy == -R || dy == R) ? 1 : ((R > 0) ? 2 * R : 1);
                for (int dx = -R; dx <= R; dx += step) {
                    int xc = cxl + dx;
                    if ((unsigned)xc >= GD) continue;
                    int cell = (zz * GD + yy) * GD + xc;
                    int base = ob[cell];
                    int num  = cb[cell];
                    for (int i = 0; i < num; ++i) body(base + i);
                }
            }
        }
    };

    // phase A: distance-only top-16 (branchless min/max bubble)
    float a[16];
    #pragma unroll
    for (int i = 0; i < 16; ++i) a[i] = 3.0e38f;
    int Rdone = 0;
    for (int R = 0; R < 48; ++R) {
        for_shell(R, [&](int sp) {
            float d = pdist(q, spos[sp]);
            if (d < a[15]) {
                a[15] = d;
                #pragma unroll
                for (int u = 15; u > 0; --u) {
                    float lo = fminf(a[u - 1], a[u]);
                    a[u]     = fmaxf(a[u - 1], a[u]);
                    a[u - 1] = lo;
                }
            }
        });
        Rdone = R;
        float rh = (float)R * HCELL;
        // points beyond shell R are at distance >= R*h (q anywhere in its cell)
        if (a[15] <= rh * rh - 1e-3f) break;
    }

    // phase B: collect all candidates with d <= tau (superset incl. ties)
    float tau = a[15];
    int hc = 0;
    for (int R = 0; R <= Rdone; ++R) {
        for_shell(R, [&](int sp) {
            float d = pdist(q, spos[sp]);
            if (d <= tau && hc < CAPB) {
                bd[t][hc] = d;
                bs[t][hc] = sp;
                hc++;
            }
        });
    }
    for (int i = 0; i < hc; ++i) bo[t][i] = sidx[bs[t][i]];

    // exact selection of 16 by (d, original index) — matches top_k tie-break
    float sx = 0.f, sy = 0.f, sz = 0.f, sd = 0.f;
    for (int k = 0; k < 16; ++k) {
        float bv = 3.0e38f;
        int bi = 0, bidx = 0x7fffffff;
        for (int i = 0; i < hc; ++i) {
            float dv = bd[t][i];
            int   ov = bo[t][i];
            if (dv < bv || (dv == bv && ov < bidx)) { bv = dv; bidx = ov; bi = i; }
        }
        float4 p = spos[bs[t][bi]];
        float rx = p.x - q.x, ry = p.y - q.y, rz = p.z - q.z;
        sx += rx; sy += ry; sz += rz;
        sd += sqrtf(__fadd_rn(__fadd_rn(__fmul_rn(rx, rx), __fmul_rn(ry, ry)), __fmul_rn(rz, rz)));
        knn[(((size_t)b << 13) + nq) * 16 + k] = bidx;
        bd[t][bi] = 3.0e38f;
    }
    const float inv16 = 0.0625f;
    spatial[((size_t)b * 4 + 0) * NPTS + nq] = sx * inv16;
    spatial[((size_t)b * 4 + 1) * NPTS + nq] = sy * inv16;
    spatial[((size_t)b * 4 + 2) * NPTS + nq] = sz * inv16;
    spatial[((size_t)b * 4 + 3) * NPTS + nq] = sd * inv16;
}

// ---------------- x[B,C,N] -> xT[B,N,C] ----------------
__global__ void transpose_k(const float* __restrict__ x, float* __restrict__ xT) {
    __shared__ float tl[32][33];
    int b = blockIdx.z;
    int n0 = blockIdx.x * 32, c0 = blockIdx.y * 32;
    int tx = threadIdx.x, ty = threadIdx.y;
    const float* xb = x + (size_t)b * 128 * NN;
    float* xtb = xT + (size_t)b * NN * 128;
    for (int i = 0; i < 32; i += 8) tl[ty + i][tx] = xb[(size_t)(c0 + ty + i) * NN + n0 + tx];
    __syncthreads();
    for (int i = 0; i < 32; i += 8) xtb[(size_t)(n0 + ty + i) * 128 + c0 + tx] = tl[tx][ty + i];
}

// ---------------- max_k(x[:,idx_k]) - x  -> md[B,128,N] ----------------
__global__ __launch_bounds__(256) void md_k(const float* __restrict__ xT,
                                            const int* __restrict__ knn,
                                            float* __restrict__ md) {
    __shared__ int ki[8][16];
    __shared__ float smd[8][132];
    int b = blockIdx.y;
    int n0 = blockIdx.x * 8;
    int tid = threadIdx.x;
    if (tid < 128) ki[tid >> 4][tid & 15] = knn[(((size_t)b << 13) + n0 + (tid >> 4)) * 16 + (tid & 15)];
    __syncthreads();
    int nl = tid >> 5;
    int c4 = (tid & 31) * 4;
    const float* xb = xT + (size_t)b * NPTS * 128;
    float4 m = make_float4(-3.0e38f, -3.0e38f, -3.0e38f, -3.0e38f);
    #pragma unroll
    for (int k = 0; k < 16; ++k) {
        const float4 g = *(const float4*)(xb + (size_t)ki[nl][k] * 128 + c4);
        m.x = fmaxf(m.x, g.x); m.y = fmaxf(m.y, g.y); m.z = fmaxf(m.z, g.z); m.w = fmaxf(m.w, g.w);
    }
    const float4 own = *(const float4*)(xb + (size_t)(n0 + nl) * 128 + c4);
    m.x -= own.x; m.y -= own.y; m.z -= own.z; m.w -= own.w;
    *(float4*)(&smd[nl][c4]) = m;
    __syncthreads();
    for (int r = 0; r < 4; ++r) {
        int c = (tid >> 3) + 32 * r;
        int n2 = tid & 7;
        md[((size_t)b * 128 + c) * NN + n0 + n2] = smd[n2][c];
    }
}

// ---------------- fold conv-bias + BN into per-channel scale/shift ----------------
__global__ void prep_k(const float* bb1, const float* g1, const float* be1, const float* m1, const float* v1,
                       const float* bb2, const float* g2, const float* be2, const float* m2, const float* v2,
                       const float* sb1, const float* gs,  const float* bes, const float* ms, const float* vs,
                       const float* sb2,
                       const float* ab1, const float* ga,  const float* bea, const float* ma, const float* va,
                       const float* ab2, float* sc) {
    int t = threadIdx.x;
    if (t < 128) {
        float i1 = g1[t] / sqrtf(v1[t] + 1e-5f);
        sc[t] = i1;        sc[128 + t] = bb1[t] * i1 + be1[t] - m1[t] * i1;
        float i2 = g2[t] / sqrtf(v2[t] + 1e-5f);
        sc[256 + t] = i2;  sc[384 + t] = bb2[t] * i2 + be2[t] - m2[t] * i2;
        sc[832 + t] = 1.0f; sc[960 + t] = ab2[t];
    }
    if (t < 32) {
        float is = gs[t] / sqrtf(vs[t] + 1e-5f);
        sc[512 + t] = is;  sc[544 + t] = sb1[t] * is + bes[t] - ms[t] * is;
    }
    if (t < 64) {
        sc[576 + t] = 1.0f; sc[640 + t] = sb2[t];
        float ia = ga[t] / sqrtf(va[t] + 1e-5f);
        sc[704 + t] = ia;  sc[768 + t] = ab1[t] * ia + bea[t] - ma[t] * ia;
    }
}

// ---------------- generic 1x1-conv (+folded BN, activation) ----------------
// ACT: 0=none, 1=relu, 2=sigmoid + fused "dout = x + y2*attn"
template <int O, int K, int TILE_N, int SPLIT, int ACT>
__global__ __launch_bounds__(256) void conv_bn(const float* __restrict__ srcA,
                                               const float* __restrict__ srcB,
                                               const float* __restrict__ W,
                                               const float* __restrict__ scale,
                                               const float* __restrict__ shift,
                                               float* __restrict__ out,
                                               const float* __restrict__ resx,
                                               const float* __restrict__ y2,
                                               float* __restrict__ dout) {
    constexpr int KC  = (K < 64) ? K : 64;
    constexpr int NT4 = TILE_N / 4;
    constexpr int O4  = O / 4;
    static_assert(NT4 * O4 == 256, "thread mapping");
    __shared__ float wT[KC][O + 4];
    __shared__ float inT[KC][TILE_N];
    int tid = threadIdx.x;
    int b = blockIdx.z;
    int n0 = blockIdx.x * TILE_N;
    int n_thr = tid % NT4;          // n fastest -> coalesced stores
    int o_thr = tid / NT4;
    float acc[4][4] = {{0.f, 0.f, 0.f, 0.f}, {0.f, 0.f, 0.f, 0.f}, {0.f, 0.f, 0.f, 0.f}, {0.f, 0.f, 0.f, 0.f}};

    for (int k0 = 0; k0 < K; k0 += KC) {
        for (int idx = tid; idx < KC * O; idx += 256) {
            int cc = idx % KC;
            int o  = idx / KC;
            wT[cc][o] = W[(size_t)o * K + k0 + cc];
        }
        for (int idx = tid; idx < KC * NT4; idx += 256) {
            int cc = idx / NT4;
            int nf = idx % NT4;
            int cg = k0 + cc;
            const float* src = (cg < SPLIT)
                ? (srcA + ((size_t)b * SPLIT + cg) * NN)
                : (srcB + ((size_t)b * (K - SPLIT) + (cg - SPLIT)) * NN);
            *(float4*)(&inT[cc][nf * 4]) = *(const float4*)(src + n0 + nf * 4);
        }
        __syncthreads();
        #pragma unroll 8
        for (int c = 0; c < KC; ++c) {
            float4 wv = *(const float4*)(&wT[c][o_thr * 4]);
            float4 iv = *(const float4*)(&inT[c][n_thr * 4]);
            acc[0][0] = fmaf(wv.x, iv.x, acc[0][0]); acc[0][1] = fmaf(wv.x, iv.y, acc[0][1]);
            acc[0][2] = fmaf(wv.x, iv.z, acc[0][2]); acc[0][3] = fmaf(wv.x, iv.w, acc[0][3]);
            acc[1][0] = fmaf(wv.y, iv.x, acc[1][0]); acc[1][1] = fmaf(wv.y, iv.y, acc[1][1]);
            acc[1][2] = fmaf(wv.y, iv.z, acc[1][2]); acc[1][3] = fmaf(wv.y, iv.w, acc[1][3]);
            acc[2][0] = fmaf(wv.z, iv.x, acc[2][0]); acc[2][1] = fmaf(wv.z, iv.y, acc[2][1]);
            acc[2][2] = fmaf(wv.z, iv.z, acc[2][2]); acc[2][3] = fmaf(wv.z, iv.w, acc[2][3]);
            acc[3][0] = fmaf(wv.w, iv.x, acc[3][0]); acc[3][1] = fmaf(wv.w, iv.y, acc[3][1]);
            acc[3][2] = fmaf(wv.w, iv.z, acc[3][2]); acc[3][3] = fmaf(wv.w, iv.w, acc[3][3]);
        }
        __syncthreads();
    }
    #pragma unroll
    for (int j = 0; j < 4; ++j) {
        int o = o_thr * 4 + j;
        float scv = scale[o], shv = shift[o];
        float4 v;
        v.x = fmaf(acc[j][0], scv, shv);
        v.y = fmaf(acc[j][1], scv, shv);
        v.z = fmaf(acc[j][2], scv, shv);
        v.w = fmaf(acc[j][3], scv, shv);
        size_t obase = ((size_t)b * O + o) * NN + n0 + n_thr * 4;
        if (ACT == 1) {
            v.x = fmaxf(v.x, 0.f); v.y = fmaxf(v.y, 0.f); v.z = fmaxf(v.z, 0.f); v.w = fmaxf(v.w, 0.f);
            *(float4*)(out + obase) = v;
        } else if (ACT == 2) {
            float4 xr = *(const float4*)(resx + obase);
            float4 yr = *(const float4*)(y2 + obase);
            v.x = xr.x + yr.x / (1.f + __expf(-v.x));
            v.y = xr.y + yr.y / (1.f + __expf(-v.y));
            v.z = xr.z + yr.z / (1.f + __expf(-v.z));
            v.w = xr.w + yr.w / (1.f + __expf(-v.w));
            *(float4*)(dout + obase) = v;
        } else {
            *(float4*)(out + obase) = v;
        }
    }
}

extern "C" void kernel_launch(void* const* d_in, const int* in_sizes, int n_in,
                              void* d_out, int out_size, void* d_ws, size_t ws_size,
                              hipStream_t stream) {
    (void)in_sizes; (void)n_in; (void)out_size; (void)ws_size;
    const float* x    = (const float*)d_in[0];
    const float* xyz  = (const float*)d_in[1];
    const float* bw1  = (const float*)d_in[2];
    const float* bb1  = (const float*)d_in[3];
    const float* bn1g = (const float*)d_in[4];
    const float* bn1b = (const float*)d_in[5];
    const float* bn1m = (const float*)d_in[6];
    const float* bn1v = (const float*)d_in[7];
    const float* bw2  = (const float*)d_in[8];
    const float* bb2  = (const float*)d_in[9];
    const float* bn2g = (const float*)d_in[10];
    const float* bn2b = (const float*)d_in[11];
    const float* bn2m = (const float*)d_in[12];
    const float* bn2v = (const float*)d_in[13];
    const float* sw1  = (const float*)d_in[14];
    const float* sb1  = (const float*)d_in[15];
    const float* sbng = (const float*)d_in[16];
    const float* sbnb = (const float*)d_in[17];
    const float* sbnm = (const float*)d_in[18];
    const float* sbnv = (const float*)d_in[19];
    const float* sw2  = (const float*)d_in[20];
    const float* sb2  = (const float*)d_in[21];
    const float* aw1  = (const float*)d_in[22];
    const float* ab1  = (const float*)d_in[23];
    const float* abng = (const float*)d_in[24];
    const float* abnb = (const float*)d_in[25];
    const float* abnm = (const float*)d_in[26];
    const float* abnv = (const float*)d_in[27];
    const float* aw2  = (const float*)d_in[28];
    const float* ab2  = (const float*)d_in[29];

    char* ws = (char*)d_ws;
    int*    cnt    = (int*)(ws + OFF_CNT);
    int*    offs   = (int*)(ws + OFF_OFFS);
    int*    cellid = (int*)(ws + OFF_CELLID);
    int*    rank   = (int*)(ws + OFF_RANK);
    float4* spos   = (float4*)(ws + OFF_SPOS);
    int*    sidx   = (int*)(ws + OFF_SIDX);
    int*    knn    = (int*)(ws + OFF_KNN);
    float*  spat   = (float*)(ws + OFF_SPATIAL);
    float*  xT     = (float*)(ws + OFF_XT);
    float*  md     = (float*)(ws + OFF_MD);
    float*  s1b    = (float*)(ws + OFF_S1);
    float*  sfb    = (float*)(ws + OFF_SF);
    float*  y1b    = (float*)(ws + OFF_Y1);
    float*  y2b    = (float*)(ws + OFF_Y2);
    float*  a1b    = (float*)(ws + OFF_A1);
    float*  sc     = (float*)(ws + OFF_SC);
    float*  dout   = (float*)d_out;

    hipMemsetAsync(cnt, 0, (size_t)TOTC * 4, stream);
    cell_build<<<dim3((NTOT + 255) / 256), 256, 0, stream>>>(xyz, cnt, cellid, rank);
    prefix_k<<<1, 1024, 0, stream>>>(cnt, offs);
    scatter_k<<<dim3((NTOT + 255) / 256), 256, 0, stream>>>(xyz, cellid, rank, offs, spos, sidx);
    knn_kernel<<<dim3(NTOT / 64), 64, 0, stream>>>(spos, sidx, cnt, offs, knn, spat);
    transpose_k<<<dim3(NPTS / 32, 128 / 32, NB), dim3(32, 8), 0, stream>>>(x, xT);
    md_k<<<dim3(NPTS / 8, NB), 256, 0, stream>>>(xT, knn, md);
    prep_k<<<1, 128, 0, stream>>>(bb1, bn1g, bn1b, bn1m, bn1v,
                                  bb2, bn2g, bn2b, bn2m, bn2v,
                                  sb1, sbng, sbnb, sbnm, sbnv,
                                  sb2,
                                  ab1, abng, abnb, abnm, abnv,
                                  ab2, sc);
    // spatial MLP: 4->32 (bn,relu), 32->64
    conv_bn<32, 4, 128, 4, 1><<<dim3(NPTS / 128, 1, NB), 256, 0, stream>>>(
        spat, spat, sw1, sc + 512, sc + 544, s1b, nullptr, nullptr, nullptr);
    conv_bn<64, 32, 64, 32, 0><<<dim3(NPTS / 64, 1, NB), 256, 0, stream>>>(
        s1b, s1b, sw2, sc + 576, sc + 640, sfb, nullptr, nullptr, nullptr);
    // boundary net: [x;md] 256->128 (bn,relu), 128->128 (bn,relu)
    conv_bn<128, 256, 32, 128, 1><<<dim3(NPTS / 32, 1, NB), 256, 0, stream>>>(
        x, md, bw1, sc + 0, sc + 128, y1b, nullptr, nullptr, nullptr);
    conv_bn<128, 128, 32, 128, 1><<<dim3(NPTS / 32, 1, NB), 256, 0, stream>>>(
        y1b, y1b, bw2, sc + 256, sc + 384, y2b, nullptr, nullptr, nullptr);
    // attention: [x;sfeat] 192->64 (bn,relu), 64->128 sigmoid + final fuse
    conv_bn<64, 192, 64, 128, 1><<<dim3(NPTS / 64, 1, NB), 256, 0, stream>>>(
        x, sfb, aw1, sc + 704, sc + 768, a1b, nullptr, nullptr, nullptr);
    conv_bn<128, 64, 32, 64, 2><<<dim3(NPTS / 32, 1, NB), 256, 0, stream>>>(
        a1b, a1b, aw2, sc + 832, sc + 960, dout, x, y2b, dout);
}

// Round 3
// 472.297 us; speedup vs baseline: 12.3577x; 12.3577x over previous
//
#include <hip/hip_runtime.h>
#include <math.h>

#define NPTS  8192
#define NB    2
#define NTOT  (NPTS*NB)
#define GD    60
#define NCELL (GD*GD*GD)
#define TOTC  (NB*NCELL)
#define HCELL 0.2f
#define INVH  5.0f
#define ORGN  (-6.0f)
#define NN    8192
#define SCAN_CHUNK 1024
#define NBLK_SCAN  ((TOTC + SCAN_CHUNK - 1) / SCAN_CHUNK)

// ---------------- workspace layout (bytes) ----------------
#define OFF_CNT     ((size_t)0)
#define OFF_OFFS    (OFF_CNT    + (size_t)TOTC*4)
#define OFF_CELLID  (OFF_OFFS   + (size_t)TOTC*4)
#define OFF_RANK    (OFF_CELLID + (size_t)NTOT*4)
#define OFF_SPOS    (OFF_RANK   + (size_t)NTOT*4)          // float4 * NTOT (w = origidx bits)
#define OFF_KNN     (OFF_SPOS   + (size_t)NTOT*16)         // int * NTOT*16
#define OFF_SPATIAL (OFF_KNN    + (size_t)NTOT*16*4)       // [B,4,N]
#define OFF_XT      (OFF_SPATIAL+ (size_t)NB*4*NPTS*4)     // [B,N,128]
#define OFF_MD      (OFF_XT     + (size_t)NB*128*NPTS*4)   // [B,128,N]
#define OFF_S1      (OFF_MD     + (size_t)NB*128*NPTS*4)   // [B,32,N]
#define OFF_SF      (OFF_S1     + (size_t)NB*32*NPTS*4)    // [B,64,N]
#define OFF_Y1      (OFF_SF     + (size_t)NB*64*NPTS*4)    // [B,128,N]
#define OFF_Y2      (OFF_Y1     + (size_t)NB*128*NPTS*4)   // [B,128,N]
#define OFF_A1      (OFF_Y2     + (size_t)NB*128*NPTS*4)   // [B,64,N]
#define OFF_SC      (OFF_A1     + (size_t)NB*64*NPTS*4)    // 1088 floats
#define OFF_BSUM    (OFF_SC     + (size_t)1088*4)          // NBLK_SCAN ints
#define OFF_BPRE    (OFF_BSUM   + (size_t)NBLK_SCAN*4)     // NBLK_SCAN ints

// Replicate reference arithmetic exactly (no fma contraction).
static __device__ __forceinline__ float sumsq3(float x, float y, float z) {
    return __fadd_rn(__fadd_rn(__fmul_rn(x, x), __fmul_rn(y, y)), __fmul_rn(z, z));
}
static __device__ __forceinline__ float pdist4(float qx, float qy, float qz, float qxx,
                                               float px, float py, float pz) {
    float pxx = sumsq3(px, py, pz);
    float dot = __fadd_rn(__fadd_rn(__fmul_rn(qx, px), __fmul_rn(qy, py)), __fmul_rn(qz, pz));
    return __fsub_rn(__fadd_rn(qxx, pxx), __fadd_rn(dot, dot));
}
// monotone unsigned key for float (handles tiny negative self-distance)
static __device__ __forceinline__ unsigned fkey(float f) {
    unsigned b = __float_as_uint(f);
    return b ^ ((unsigned)(((int)b) >> 31) | 0x80000000u);
}
static __device__ __forceinline__ unsigned long long shflx64(unsigned long long v, int m) {
    unsigned lo = __shfl_xor((unsigned)v, m, 64);
    unsigned hi = __shfl_xor((unsigned)(v >> 32), m, 64);
    return ((unsigned long long)hi << 32) | lo;
}

// ---------------- grid build ----------------
__global__ void cell_build(const float* __restrict__ xyz, int* __restrict__ cnt,
                           int* __restrict__ cellid, int* __restrict__ rank) {
    int t = blockIdx.x * 256 + threadIdx.x;
    if (t >= NTOT) return;
    const float* p = xyz + (size_t)t * 3;
    float x = p[0], y = p[1], z = p[2];
    int cx = min(GD - 1, max(0, (int)floorf((x - ORGN) * INVH)));
    int cy = min(GD - 1, max(0, (int)floorf((y - ORGN) * INVH)));
    int cz = min(GD - 1, max(0, (int)floorf((z - ORGN) * INVH)));
    int gcell = (t >> 13) * NCELL + (cz * GD + cy) * GD + cx;
    rank[t] = atomicAdd(&cnt[gcell], 1);
    cellid[t] = gcell;
}

// -------- hierarchical exclusive scan of cnt[TOTC] -> offs[TOTC] --------
__global__ __launch_bounds__(256) void scan_sums(const int* __restrict__ cnt, int* __restrict__ bsum) {
    __shared__ int red[256];
    int blk = blockIdx.x, t = threadIdx.x;
    int i0 = blk * SCAN_CHUNK + t * 4;
    int s = 0;
    if (i0 + 3 < TOTC) {
        int4 v = *(const int4*)(cnt + i0);
        s = v.x + v.y + v.z + v.w;
    } else {
        for (int j = 0; j < 4; ++j) if (i0 + j < TOTC) s += cnt[i0 + j];
    }
    red[t] = s;
    __syncthreads();
    for (int d = 128; d > 0; d >>= 1) {
        if (t < d) red[t] += red[t + d];
        __syncthreads();
    }
    if (t == 0) bsum[blk] = red[0];
}

__global__ __launch_bounds__(512) void scan_top(const int* __restrict__ bsum, int* __restrict__ bpre) {
    __shared__ int ps[512];
    int t = threadIdx.x;
    int v = (t < NBLK_SCAN) ? bsum[t] : 0;
    ps[t] = v;
    __syncthreads();
    for (int d = 1; d < 512; d <<= 1) {
        int u = 0;
        if (t >= d) u = ps[t - d];
        __syncthreads();
        ps[t] += u;
        __syncthreads();
    }
    if (t < NBLK_SCAN) bpre[t] = ps[t] - v;   // exclusive
}

__global__ __launch_bounds__(256) void scan_write(const int* __restrict__ cnt, const int* __restrict__ bpre,
                                                  int* __restrict__ offs) {
    __shared__ int ps[256];
    int blk = blockIdx.x, t = threadIdx.x;
    int i0 = blk * SCAN_CHUNK + t * 4;
    int a = 0, b = 0, c = 0, d = 0;
    if (i0 + 3 < TOTC) {
        int4 v = *(const int4*)(cnt + i0);
        a = v.x; b = v.y; c = v.z; d = v.w;
    } else {
        if (i0 + 0 < TOTC) a = cnt[i0 + 0];
        if (i0 + 1 < TOTC) b = cnt[i0 + 1];
        if (i0 + 2 < TOTC) c = cnt[i0 + 2];
        if (i0 + 3 < TOTC) d = cnt[i0 + 3];
    }
    int s = a + b + c + d;
    ps[t] = s;
    __syncthreads();
    for (int dd = 1; dd < 256; dd <<= 1) {
        int u = 0;
        if (t >= dd) u = ps[t - dd];
        __syncthreads();
        ps[t] += u;
        __syncthreads();
    }
    int base = bpre[blk] + ps[t] - s;
    if (i0 + 0 < TOTC) offs[i0 + 0] = base;
    if (i0 + 1 < TOTC) offs[i0 + 1] = base + a;
    if (i0 + 2 < TOTC) offs[i0 + 2] = base + a + b;
    if (i0 + 3 < TOTC) offs[i0 + 3] = base + a + b + c;
}

__global__ void scatter_k(const float* __restrict__ xyz, const int* __restrict__ cellid,
                          const int* __restrict__ rank, const int* __restrict__ offs,
                          float4* __restrict__ spos) {
    int t = blockIdx.x * 256 + threadIdx.x;
    if (t >= NTOT) return;
    const float* p = xyz + (size_t)t * 3;
    float x = p[0], y = p[1], z = p[2];
    int pos = offs[cellid[t]] + rank[t];
    spos[pos] = make_float4(x, y, z, __int_as_float(t & (NPTS - 1)));
}

// decode u-th cell of Chebyshev shell R (R>=1); S(R)=24R^2+2
static __device__ __forceinline__ void shell_decode(int R, int u, int& dx, int& dy, int& dz) {
    int L = 2 * R + 1, P = L * L;
    if (u < 2 * P) {
        int v = (u < P) ? u : u - P;
        dz = (u < P) ? -R : R;
        dx = v % L - R;
        dy = v / L - R;
    } else {
        int w = u - 2 * P;
        int ring = w / (8 * R);
        int p = w - ring * 8 * R;
        dz = ring - (R - 1);
        if (p < 2 * R)      { dx = p - R;            dy = -R; }
        else if (p < 4 * R) { dx = R;                dy = p - 3 * R; }
        else if (p < 6 * R) { dx = 5 * R - p;        dy = R; }
        else                { dx = -R;               dy = 7 * R - p; }
    }
}

// ---------------- exact KNN: one wave per query ----------------
__global__ __launch_bounds__(256) void knn_kernel(const float4* __restrict__ spos,
                                                  const int* __restrict__ cnt,
                                                  const int* __restrict__ offs,
                                                  int* __restrict__ knn,
                                                  float* __restrict__ spatial) {
    int lane = threadIdx.x & 63;
    int wv   = threadIdx.x >> 6;
    int s    = blockIdx.x * 4 + wv;       // query slot in sorted order
    float4 q = spos[s];
    float qx = q.x, qy = q.y, qz = q.z;
    float qxx = sumsq3(qx, qy, qz);
    int b  = s >> 13;
    int nq = __float_as_int(q.w);
    int cx = min(GD - 1, max(0, (int)floorf((qx - ORGN) * INVH)));
    int cy = min(GD - 1, max(0, (int)floorf((qy - ORGN) * INVH)));
    int cz = min(GD - 1, max(0, (int)floorf((qz - ORGN) * INVH)));
    const int* cb = cnt  + b * NCELL;
    const int* ob = offs + b * NCELL;     // NOTE: offs is a GLOBAL scan; base below is a global slot

    unsigned long long a[16];
    #pragma unroll
    for (int i = 0; i < 16; ++i) a[i] = ~0ULL;

    int R = 0;
    while (true) {
        int S = (R == 0) ? 1 : 24 * R * R + 2;
        for (int u0 = 0; u0 < S; u0 += 64) {
            int u = u0 + lane;
            int num = 0, base = 0;
            if (u < S) {
                int dx = 0, dy = 0, dz = 0;
                if (R > 0) shell_decode(R, u, dx, dy, dz);
                int xc = cx + dx, yc = cy + dy, zc = cz + dz;
                if ((unsigned)xc < GD && (unsigned)yc < GD && (unsigned)zc < GD) {
                    int cell = (zc * GD + yc) * GD + xc;
                    num  = cb[cell];
                    base = ob[cell];
                }
            }
            for (int i = 0; i < num; ++i) {
                float4 p = spos[base + i];          // base is global (includes batch offset)
                float d = pdist4(qx, qy, qz, qxx, p.x, p.y, p.z);
                int oi = __float_as_int(p.w);
                unsigned long long key = ((unsigned long long)fkey(d) << 27)
                                       | ((unsigned long long)(unsigned)oi << 14)
                                       | (unsigned)(base + i);
                if (key < a[15]) {
                    a[15] = key;
                    #pragma unroll
                    for (int t2 = 15; t2 > 0; --t2) {
                        unsigned long long lo = (a[t2 - 1] < a[t2]) ? a[t2 - 1] : a[t2];
                        unsigned long long hi = (a[t2 - 1] < a[t2]) ? a[t2] : a[t2 - 1];
                        a[t2 - 1] = lo; a[t2] = hi;
                    }
                }
            }
        }
        // stop: >=16 wave-wide candidates strictly inside guaranteed radius R*h
        float rh = (float)R * HCELL;
        float thr = rh * rh - 1e-3f;
        unsigned long long tkey = ((unsigned long long)(fkey(thr) + 1u)) << 27;
        int c = 0;
        #pragma unroll
        for (int i = 0; i < 16; ++i) c += (a[i] < tkey) ? 1 : 0;
        for (int o = 32; o > 0; o >>= 1) c += __shfl_xor(c, o, 64);
        if (c >= 16 || R > 59) break;
        ++R;
    }

    // exact global top-16: 16 rounds of wave-wide u64 argmin over sorted heads
    unsigned long long keep = ~0ULL;
    for (int k = 0; k < 16; ++k) {
        unsigned long long m = a[0];
        for (int o = 32; o > 0; o >>= 1) {
            unsigned long long pv = shflx64(m, o);
            m = (pv < m) ? pv : m;
        }
        unsigned long long bal = __ballot(a[0] == m);
        int wl = __ffsll((long long)bal) - 1;
        if (lane == wl) {
            #pragma unroll
            for (int i = 0; i < 15; ++i) a[i] = a[i + 1];
            a[15] = ~0ULL;
        }
        if (lane == k) keep = m;
    }

    float rx = 0.f, ry = 0.f, rz = 0.f, rd = 0.f;
    if (lane < 16) {
        int sp = (int)(keep & 0x3FFFu);
        int oi = (int)((keep >> 14) & 0x1FFFu);
        float4 p = spos[sp];
        rx = p.x - qx; ry = p.y - qy; rz = p.z - qz;
        rd = sqrtf(__fadd_rn(__fadd_rn(__fmul_rn(rx, rx), __fmul_rn(ry, ry)), __fmul_rn(rz, rz)));
        knn[(((size_t)b << 13) + nq) * 16 + lane] = oi;
    }
    for (int o = 8; o > 0; o >>= 1) {
        rx += __shfl_xor(rx, o, 64);
        ry += __shfl_xor(ry, o, 64);
        rz += __shfl_xor(rz, o, 64);
        rd += __shfl_xor(rd, o, 64);
    }
    if (lane == 0) {
        const float inv16 = 0.0625f;
        spatial[((size_t)b * 4 + 0) * NPTS + nq] = rx * inv16;
        spatial[((size_t)b * 4 + 1) * NPTS + nq] = ry * inv16;
        spatial[((size_t)b * 4 + 2) * NPTS + nq] = rz * inv16;
        spatial[((size_t)b * 4 + 3) * NPTS + nq] = rd * inv16;
    }
}

// ---------------- x[B,C,N] -> xT[B,N,C] ----------------
__global__ void transpose_k(const float* __restrict__ x, float* __restrict__ xT) {
    __shared__ float tl[32][33];
    int b = blockIdx.z;
    int n0 = blockIdx.x * 32, c0 = blockIdx.y * 32;
    int tx = threadIdx.x, ty = threadIdx.y;
    const float* xb = x + (size_t)b * 128 * NN;
    float* xtb = xT + (size_t)b * NN * 128;
    for (int i = 0; i < 32; i += 8) tl[ty + i][tx] = xb[(size_t)(c0 + ty + i) * NN + n0 + tx];
    __syncthreads();
    for (int i = 0; i < 32; i += 8) xtb[(size_t)(n0 + ty + i) * 128 + c0 + tx] = tl[tx][ty + i];
}

// ---------------- max_k(x[:,idx_k]) - x  -> md[B,128,N] ----------------
__global__ __launch_bounds__(256) void md_k(const float* __restrict__ xT,
                                            const int* __restrict__ knn,
                                            float* __restrict__ md) {
    __shared__ int ki[8][16];
    __shared__ float smd[8][132];
    int b = blockIdx.y;
    int n0 = blockIdx.x * 8;
    int tid = threadIdx.x;
    if (tid < 128) ki[tid >> 4][tid & 15] = knn[(((size_t)b << 13) + n0 + (tid >> 4)) * 16 + (tid & 15)];
    __syncthreads();
    int nl = tid >> 5;
    int c4 = (tid & 31) * 4;
    const float* xb = xT + (size_t)b * NPTS * 128;
    float4 m = make_float4(-3.0e38f, -3.0e38f, -3.0e38f, -3.0e38f);
    #pragma unroll
    for (int k = 0; k < 16; ++k) {
        const float4 g = *(const float4*)(xb + (size_t)ki[nl][k] * 128 + c4);
        m.x = fmaxf(m.x, g.x); m.y = fmaxf(m.y, g.y); m.z = fmaxf(m.z, g.z); m.w = fmaxf(m.w, g.w);
    }
    const float4 own = *(const float4*)(xb + (size_t)(n0 + nl) * 128 + c4);
    m.x -= own.x; m.y -= own.y; m.z -= own.z; m.w -= own.w;
    *(float4*)(&smd[nl][c4]) = m;
    __syncthreads();
    for (int r = 0; r < 4; ++r) {
        int c = (tid >> 3) + 32 * r;
        int n2 = tid & 7;
        md[((size_t)b * 128 + c) * NN + n0 + n2] = smd[n2][c];
    }
}

// ---------------- fold conv-bias + BN into per-channel scale/shift ----------------
__global__ void prep_k(const float* bb1, const float* g1, const float* be1, const float* m1, const float* v1,
                       const float* bb2, const float* g2, const float* be2, const float* m2, const float* v2,
                       const float* sb1, const float* gs,  const float* bes, const float* ms, const float* vs,
                       const float* sb2,
                       const float* ab1, const float* ga,  const float* bea, const float* ma, const float* va,
                       const float* ab2, float* sc) {
    int t = threadIdx.x;
    if (t < 128) {
        float i1 = g1[t] / sqrtf(v1[t] + 1e-5f);
        sc[t] = i1;        sc[128 + t] = bb1[t] * i1 + be1[t] - m1[t] * i1;
        float i2 = g2[t] / sqrtf(v2[t] + 1e-5f);
        sc[256 + t] = i2;  sc[384 + t] = bb2[t] * i2 + be2[t] - m2[t] * i2;
        sc[832 + t] = 1.0f; sc[960 + t] = ab2[t];
    }
    if (t < 32) {
        float is = gs[t] / sqrtf(vs[t] + 1e-5f);
        sc[512 + t] = is;  sc[544 + t] = sb1[t] * is + bes[t] - ms[t] * is;
    }
    if (t < 64) {
        sc[576 + t] = 1.0f; sc[640 + t] = sb2[t];
        float ia = ga[t] / sqrtf(va[t] + 1e-5f);
        sc[704 + t] = ia;  sc[768 + t] = ab1[t] * ia + bea[t] - ma[t] * ia;
    }
}

// ---------------- generic 1x1-conv (+folded BN, activation) ----------------
// ACT: 0=none, 1=relu, 2=sigmoid + fused "dout = x + y2*attn"
template <int O, int K, int TILE_N, int SPLIT, int ACT>
__global__ __launch_bounds__(256) void conv_bn(const float* __restrict__ srcA,
                                               const float* __restrict__ srcB,
                                               const float* __restrict__ W,
                                               const float* __restrict__ scale,
                                               const float* __restrict__ shift,
                                               float* __restrict__ out,
                                               const float* __restrict__ resx,
                                               const float* __restrict__ y2,
                                               float* __restrict__ dout) {
    constexpr int KC  = (K < 64) ? K : 64;
    constexpr int NT4 = TILE_N / 4;
    constexpr int O4  = O / 4;
    static_assert(NT4 * O4 == 256, "thread mapping");
    __shared__ float wT[KC][O + 4];
    __shared__ float inT[KC][TILE_N];
    int tid = threadIdx.x;
    int b = blockIdx.z;
    int n0 = blockIdx.x * TILE_N;
    int n_thr = tid % NT4;          // n fastest -> coalesced stores
    int o_thr = tid / NT4;
    float acc[4][4] = {{0.f, 0.f, 0.f, 0.f}, {0.f, 0.f, 0.f, 0.f}, {0.f, 0.f, 0.f, 0.f}, {0.f, 0.f, 0.f, 0.f}};

    for (int k0 = 0; k0 < K; k0 += KC) {
        for (int idx = tid; idx < KC * O; idx += 256) {
            int cc = idx % KC;
            int o  = idx / KC;
            wT[cc][o] = W[(size_t)o * K + k0 + cc];
        }
        for (int idx = tid; idx < KC * NT4; idx += 256) {
            int cc = idx / NT4;
            int nf = idx % NT4;
            int cg = k0 + cc;
            const float* src = (cg < SPLIT)
                ? (srcA + ((size_t)b * SPLIT + cg) * NN)
                : (srcB + ((size_t)b * (K - SPLIT) + (cg - SPLIT)) * NN);
            *(float4*)(&inT[cc][nf * 4]) = *(const float4*)(src + n0 + nf * 4);
        }
        __syncthreads();
        #pragma unroll 8
        for (int c = 0; c < KC; ++c) {
            float4 wv = *(const float4*)(&wT[c][o_thr * 4]);
            float4 iv = *(const float4*)(&inT[c][n_thr * 4]);
            acc[0][0] = fmaf(wv.x, iv.x, acc[0][0]); acc[0][1] = fmaf(wv.x, iv.y, acc[0][1]);
            acc[0][2] = fmaf(wv.x, iv.z, acc[0][2]); acc[0][3] = fmaf(wv.x, iv.w, acc[0][3]);
            acc[1][0] = fmaf(wv.y, iv.x, acc[1][0]); acc[1][1] = fmaf(wv.y, iv.y, acc[1][1]);
            acc[1][2] = fmaf(wv.y, iv.z, acc[1][2]); acc[1][3] = fmaf(wv.y, iv.w, acc[1][3]);
            acc[2][0] = fmaf(wv.z, iv.x, acc[2][0]); acc[2][1] = fmaf(wv.z, iv.y, acc[2][1]);
            acc[2][2] = fmaf(wv.z, iv.z, acc[2][2]); acc[2][3] = fmaf(wv.z, iv.w, acc[2][3]);
            acc[3][0] = fmaf(wv.w, iv.x, acc[3][0]); acc[3][1] = fmaf(wv.w, iv.y, acc[3][1]);
            acc[3][2] = fmaf(wv.w, iv.z, acc[3][2]); acc[3][3] = fmaf(wv.w, iv.w, acc[3][3]);
        }
        __syncthreads();
    }
    #pragma unroll
    for (int j = 0; j < 4; ++j) {
        int o = o_thr * 4 + j;
        float scv = scale[o], shv = shift[o];
        float4 v;
        v.x = fmaf(acc[j][0], scv, shv);
        v.y = fmaf(acc[j][1], scv, shv);
        v.z = fmaf(acc[j][2], scv, shv);
        v.w = fmaf(acc[j][3], scv, shv);
        size_t obase = ((size_t)b * O + o) * NN + n0 + n_thr * 4;
        if (ACT == 1) {
            v.x = fmaxf(v.x, 0.f); v.y = fmaxf(v.y, 0.f); v.z = fmaxf(v.z, 0.f); v.w = fmaxf(v.w, 0.f);
            *(float4*)(out + obase) = v;
        } else if (ACT == 2) {
            float4 xr = *(const float4*)(resx + obase);
            float4 yr = *(const float4*)(y2 + obase);
            v.x = xr.x + yr.x / (1.f + __expf(-v.x));
            v.y = xr.y + yr.y / (1.f + __expf(-v.y));
            v.z = xr.z + yr.z / (1.f + __expf(-v.z));
            v.w = xr.w + yr.w / (1.f + __expf(-v.w));
            *(float4*)(dout + obase) = v;
        } else {
            *(float4*)(out + obase) = v;
        }
    }
}

extern "C" void kernel_launch(void* const* d_in, const int* in_sizes, int n_in,
                              void* d_out, int out_size, void* d_ws, size_t ws_size,
                              hipStream_t stream) {
    (void)in_sizes; (void)n_in; (void)out_size; (void)ws_size;
    const float* x    = (const float*)d_in[0];
    const float* xyz  = (const float*)d_in[1];
    const float* bw1  = (const float*)d_in[2];
    const float* bb1  = (const float*)d_in[3];
    const float* bn1g = (const float*)d_in[4];
    const float* bn1b = (const float*)d_in[5];
    const float* bn1m = (const float*)d_in[6];
    const float* bn1v = (const float*)d_in[7];
    const float* bw2  = (const float*)d_in[8];
    const float* bb2  = (const float*)d_in[9];
    const float* bn2g = (const float*)d_in[10];
    const float* bn2b = (const float*)d_in[11];
    const float* bn2m = (const float*)d_in[12];
    const float* bn2v = (const float*)d_in[13];
    const float* sw1  = (const float*)d_in[14];
    const float* sb1  = (const float*)d_in[15];
    const float* sbng = (const float*)d_in[16];
    const float* sbnb = (const float*)d_in[17];
    const float* sbnm = (const float*)d_in[18];
    const float* sbnv = (const float*)d_in[19];
    const float* sw2  = (const float*)d_in[20];
    const float* sb2  = (const float*)d_in[21];
    const float* aw1  = (const float*)d_in[22];
    const float* ab1  = (const float*)d_in[23];
    const float* abng = (const float*)d_in[24];
    const float* abnb = (const float*)d_in[25];
    const float* abnm = (const float*)d_in[26];
    const float* abnv = (const float*)d_in[27];
    const float* aw2  = (const float*)d_in[28];
    const float* ab2  = (const float*)d_in[29];

    char* ws = (char*)d_ws;
    int*    cnt    = (int*)(ws + OFF_CNT);
    int*    offs   = (int*)(ws + OFF_OFFS);
    int*    cellid = (int*)(ws + OFF_CELLID);
    int*    rank   = (int*)(ws + OFF_RANK);
    float4* spos   = (float4*)(ws + OFF_SPOS);
    int*    knn    = (int*)(ws + OFF_KNN);
    float*  spat   = (float*)(ws + OFF_SPATIAL);
    float*  xT     = (float*)(ws + OFF_XT);
    float*  md     = (float*)(ws + OFF_MD);
    float*  s1b    = (float*)(ws + OFF_S1);
    float*  sfb    = (float*)(ws + OFF_SF);
    float*  y1b    = (float*)(ws + OFF_Y1);
    float*  y2b    = (float*)(ws + OFF_Y2);
    float*  a1b    = (float*)(ws + OFF_A1);
    float*  sc     = (float*)(ws + OFF_SC);
    int*    bsum   = (int*)(ws + OFF_BSUM);
    int*    bpre   = (int*)(ws + OFF_BPRE);
    float*  dout   = (float*)d_out;

    hipMemsetAsync(cnt, 0, (size_t)TOTC * 4, stream);
    cell_build<<<dim3((NTOT + 255) / 256), 256, 0, stream>>>(xyz, cnt, cellid, rank);
    scan_sums<<<dim3(NBLK_SCAN), 256, 0, stream>>>(cnt, bsum);
    scan_top<<<dim3(1), 512, 0, stream>>>(bsum, bpre);
    scan_write<<<dim3(NBLK_SCAN), 256, 0, stream>>>(cnt, bpre, offs);
    scatter_k<<<dim3((NTOT + 255) / 256), 256, 0, stream>>>(xyz, cellid, rank, offs, spos);
    knn_kernel<<<dim3(NTOT / 4), 256, 0, stream>>>(spos, cnt, offs, knn, spat);
    transpose_k<<<dim3(NPTS / 32, 128 / 32, NB), dim3(32, 8), 0, stream>>>(x, xT);
    md_k<<<dim3(NPTS / 8, NB), 256, 0, stream>>>(xT, knn, md);
    prep_k<<<1, 128, 0, stream>>>(bb1, bn1g, bn1b, bn1m, bn1v,
                                  bb2, bn2g, bn2b, bn2m, bn2v,
                                  sb1, sbng, sbnb, sbnm, sbnv,
                                  sb2,
                                  ab1, abng, abnb, abnm, abnv,
                                  ab2, sc);
    // spatial MLP: 4->32 (bn,relu), 32->64
    conv_bn<32, 4, 128, 4, 1><<<dim3(NPTS / 128, 1, NB), 256, 0, stream>>>(
        spat, spat, sw1, sc + 512, sc + 544, s1b, nullptr, nullptr, nullptr);
    conv_bn<64, 32, 64, 32, 0><<<dim3(NPTS / 64, 1, NB), 256, 0, stream>>>(
        s1b, s1b, sw2, sc + 576, sc + 640, sfb, nullptr, nullptr, nullptr);
    // boundary net: [x;md] 256->128 (bn,relu), 128->128 (bn,relu)
    conv_bn<128, 256, 32, 128, 1><<<dim3(NPTS / 32, 1, NB), 256, 0, stream>>>(
        x, md, bw1, sc + 0, sc + 128, y1b, nullptr, nullptr, nullptr);
    conv_bn<128, 128, 32, 128, 1><<<dim3(NPTS / 32, 1, NB), 256, 0, stream>>>(
        y1b, y1b, bw2, sc + 256, sc + 384, y2b, nullptr, nullptr, nullptr);
    // attention: [x;sfeat] 192->64 (bn,relu), 64->128 sigmoid + final fuse
    conv_bn<64, 192, 64, 128, 1><<<dim3(NPTS / 64, 1, NB), 256, 0, stream>>>(
        x, sfb, aw1, sc + 704, sc + 768, a1b, nullptr, nullptr, nullptr);
    conv_bn<128, 64, 32, 64, 2><<<dim3(NPTS / 32, 1, NB), 256, 0, stream>>>(
        a1b, a1b, aw2, sc + 832, sc + 960, dout, x, y2b, dout);
}

// Round 5
// 467.368 us; speedup vs baseline: 12.4880x; 1.0105x over previous
//
#include <hip/hip_runtime.h>
#include <math.h>

#define NPTS  8192
#define NB    2
#define NTOT  (NPTS*NB)
#define GD    60
#define NCELL (GD*GD*GD)
#define TOTC  (NB*NCELL)
#define HCELL 0.2f
#define INVH  5.0f
#define ORGN  (-6.0f)
#define NN    8192
#define SCAN_CHUNK 1024
#define NBLK_SCAN  ((TOTC + SCAN_CHUNK - 1) / SCAN_CHUNK)

// ---------------- workspace layout (bytes) ----------------
#define OFF_CNT     ((size_t)0)
#define OFF_OFFS    (OFF_CNT    + (size_t)TOTC*4)
#define OFF_CELLID  (OFF_OFFS   + (size_t)TOTC*4)
#define OFF_RANK    (OFF_CELLID + (size_t)NTOT*4)
#define OFF_SPOS    (OFF_RANK   + (size_t)NTOT*4)          // float4 * NTOT (w = origidx bits)
#define OFF_KNN     (OFF_SPOS   + (size_t)NTOT*16)         // int * NTOT*16
#define OFF_SPATIAL (OFF_KNN    + (size_t)NTOT*16*4)       // [B,4,N]
#define OFF_XT      (OFF_SPATIAL+ (size_t)NB*4*NPTS*4)     // [B,N,128]
#define OFF_MD      (OFF_XT     + (size_t)NB*128*NPTS*4)   // [B,128,N]
#define OFF_S1      (OFF_MD     + (size_t)NB*128*NPTS*4)   // [B,32,N]
#define OFF_SF      (OFF_S1     + (size_t)NB*32*NPTS*4)    // [B,64,N]
#define OFF_Y1      (OFF_SF     + (size_t)NB*64*NPTS*4)    // [B,128,N]
#define OFF_Y2      (OFF_Y1     + (size_t)NB*128*NPTS*4)   // [B,128,N]
#define OFF_A1      (OFF_Y2     + (size_t)NB*128*NPTS*4)   // [B,64,N]
#define OFF_SC      (OFF_A1     + (size_t)NB*64*NPTS*4)    // 1088 floats
#define OFF_BSUM    (OFF_SC     + (size_t)1088*4)          // NBLK_SCAN ints
#define OFF_BPRE    (OFF_BSUM   + (size_t)NBLK_SCAN*4)     // NBLK_SCAN ints

// Replicate reference arithmetic exactly (no fma contraction).
static __device__ __forceinline__ float sumsq3(float x, float y, float z) {
    return __fadd_rn(__fadd_rn(__fmul_rn(x, x), __fmul_rn(y, y)), __fmul_rn(z, z));
}
static __device__ __forceinline__ float pdist4(float qx, float qy, float qz, float qxx,
                                               float px, float py, float pz) {
    float pxx = sumsq3(px, py, pz);
    float dot = __fadd_rn(__fadd_rn(__fmul_rn(qx, px), __fmul_rn(qy, py)), __fmul_rn(qz, pz));
    return __fsub_rn(__fadd_rn(qxx, pxx), __fadd_rn(dot, dot));
}
// monotone unsigned key for float (handles tiny negative self-distance)
static __device__ __forceinline__ unsigned fkey(float f) {
    unsigned b = __float_as_uint(f);
    return b ^ ((unsigned)(((int)b) >> 31) | 0x80000000u);
}
static __device__ __forceinline__ unsigned long long shflx64(unsigned long long v, int m) {
    unsigned lo = __shfl_xor((unsigned)v, m, 64);
    unsigned hi = __shfl_xor((unsigned)(v >> 32), m, 64);
    return ((unsigned long long)hi << 32) | lo;
}

// ---------------- grid build ----------------
__global__ void cell_build(const float* __restrict__ xyz, int* __restrict__ cnt,
                           int* __restrict__ cellid, int* __restrict__ rank) {
    int t = blockIdx.x * 256 + threadIdx.x;
    if (t >= NTOT) return;
    const float* p = xyz + (size_t)t * 3;
    float x = p[0], y = p[1], z = p[2];
    int cx = min(GD - 1, max(0, (int)floorf((x - ORGN) * INVH)));
    int cy = min(GD - 1, max(0, (int)floorf((y - ORGN) * INVH)));
    int cz = min(GD - 1, max(0, (int)floorf((z - ORGN) * INVH)));
    int gcell = (t >> 13) * NCELL + (cz * GD + cy) * GD + cx;
    rank[t] = atomicAdd(&cnt[gcell], 1);
    cellid[t] = gcell;
}

// -------- hierarchical exclusive scan of cnt[TOTC] -> offs[TOTC] --------
__global__ __launch_bounds__(256) void scan_sums(const int* __restrict__ cnt, int* __restrict__ bsum) {
    __shared__ int red[256];
    int blk = blockIdx.x, t = threadIdx.x;
    int i0 = blk * SCAN_CHUNK + t * 4;
    int s = 0;
    if (i0 + 3 < TOTC) {
        int4 v = *(const int4*)(cnt + i0);
        s = v.x + v.y + v.z + v.w;
    } else {
        for (int j = 0; j < 4; ++j) if (i0 + j < TOTC) s += cnt[i0 + j];
    }
    red[t] = s;
    __syncthreads();
    for (int d = 128; d > 0; d >>= 1) {
        if (t < d) red[t] += red[t + d];
        __syncthreads();
    }
    if (t == 0) bsum[blk] = red[0];
}

__global__ __launch_bounds__(512) void scan_top(const int* __restrict__ bsum, int* __restrict__ bpre) {
    __shared__ int ps[512];
    int t = threadIdx.x;
    int v = (t < NBLK_SCAN) ? bsum[t] : 0;
    ps[t] = v;
    __syncthreads();
    for (int d = 1; d < 512; d <<= 1) {
        int u = 0;
        if (t >= d) u = ps[t - d];
        __syncthreads();
        ps[t] += u;
        __syncthreads();
    }
    if (t < NBLK_SCAN) bpre[t] = ps[t] - v;   // exclusive
}

__global__ __launch_bounds__(256) void scan_write(const int* __restrict__ cnt, const int* __restrict__ bpre,
                                                  int* __restrict__ offs) {
    __shared__ int ps[256];
    int blk = blockIdx.x, t = threadIdx.x;
    int i0 = blk * SCAN_CHUNK + t * 4;
    int a = 0, b = 0, c = 0, d = 0;
    if (i0 + 3 < TOTC) {
        int4 v = *(const int4*)(cnt + i0);
        a = v.x; b = v.y; c = v.z; d = v.w;
    } else {
        if (i0 + 0 < TOTC) a = cnt[i0 + 0];
        if (i0 + 1 < TOTC) b = cnt[i0 + 1];
        if (i0 + 2 < TOTC) c = cnt[i0 + 2];
        if (i0 + 3 < TOTC) d = cnt[i0 + 3];
    }
    int s = a + b + c + d;
    ps[t] = s;
    __syncthreads();
    for (int dd = 1; dd < 256; dd <<= 1) {
        int u = 0;
        if (t >= dd) u = ps[t - dd];
        __syncthreads();
        ps[t] += u;
        __syncthreads();
    }
    int base = bpre[blk] + ps[t] - s;
    if (i0 + 0 < TOTC) offs[i0 + 0] = base;
    if (i0 + 1 < TOTC) offs[i0 + 1] = base + a;
    if (i0 + 2 < TOTC) offs[i0 + 2] = base + a + b;
    if (i0 + 3 < TOTC) offs[i0 + 3] = base + a + b + c;
}

__global__ void scatter_k(const float* __restrict__ xyz, const int* __restrict__ cellid,
                          const int* __restrict__ rank, const int* __restrict__ offs,
                          float4* __restrict__ spos) {
    int t = blockIdx.x * 256 + threadIdx.x;
    if (t >= NTOT) return;
    const float* p = xyz + (size_t)t * 3;
    float x = p[0], y = p[1], z = p[2];
    int pos = offs[cellid[t]] + rank[t];
    spos[pos] = make_float4(x, y, z, __int_as_float(t & (NPTS - 1)));
}

// decode u-th cell of Chebyshev shell R (R>=1); S(R)=24R^2+2
static __device__ __forceinline__ void shell_decode(int R, int u, int& dx, int& dy, int& dz) {
    int L = 2 * R + 1, P = L * L;
    if (u < 2 * P) {
        int v = (u < P) ? u : u - P;
        dz = (u < P) ? -R : R;
        dx = v % L - R;
        dy = v / L - R;
    } else {
        int w = u - 2 * P;
        int ring = w / (8 * R);
        int p = w - ring * 8 * R;
        dz = ring - (R - 1);
        if (p < 2 * R)      { dx = p - R;            dy = -R; }
        else if (p < 4 * R) { dx = R;                dy = p - 3 * R; }
        else if (p < 6 * R) { dx = 5 * R - p;        dy = R; }
        else                { dx = -R;               dy = 7 * R - p; }
    }
}

// ---------------- exact KNN: one wave per query (R3-proven scanner) ----------------
// Changes vs R3 (bisection of R4's failure): (1) stop threshold uses the exact
// box-face margin instead of (R*h)^2 — after scanning shells 0..R, any unscanned
// point lies beyond a face plane of the box, so dist >= min face margin.
// (2) __launch_bounds__(256,4): allow 128 VGPR so a[16] (32 VGPRs of sorted keys)
// stays in registers instead of scratch (R3 compiled to 40 VGPR => spilled).
__global__ __launch_bounds__(256, 4) void knn_kernel(const float4* __restrict__ spos,
                                                     const int* __restrict__ cnt,
                                                     const int* __restrict__ offs,
                                                     int* __restrict__ knn,
                                                     float* __restrict__ spatial) {
    int lane = threadIdx.x & 63;
    int wv   = threadIdx.x >> 6;
    int s    = blockIdx.x * 4 + wv;       // query slot in sorted order
    float4 q = spos[s];
    float qx = q.x, qy = q.y, qz = q.z;
    float qxx = sumsq3(qx, qy, qz);
    int b  = s >> 13;
    int nq = __float_as_int(q.w);
    int cx = min(GD - 1, max(0, (int)floorf((qx - ORGN) * INVH)));
    int cy = min(GD - 1, max(0, (int)floorf((qy - ORGN) * INVH)));
    int cz = min(GD - 1, max(0, (int)floorf((qz - ORGN) * INVH)));
    const int* cb = cnt  + b * NCELL;
    const int* ob = offs + b * NCELL;     // offs is a GLOBAL scan; base below is a global slot

    unsigned long long a[16];
    #pragma unroll
    for (int i = 0; i < 16; ++i) a[i] = ~0ULL;

    int R = 0;
    while (true) {
        int S = (R == 0) ? 1 : 24 * R * R + 2;
        for (int u0 = 0; u0 < S; u0 += 64) {
            int u = u0 + lane;
            int num = 0, base = 0;
            if (u < S) {
                int dx = 0, dy = 0, dz = 0;
                if (R > 0) shell_decode(R, u, dx, dy, dz);
                int xc = cx + dx, yc = cy + dy, zc = cz + dz;
                if ((unsigned)xc < GD && (unsigned)yc < GD && (unsigned)zc < GD) {
                    int cell = (zc * GD + yc) * GD + xc;
                    num  = cb[cell];
                    base = ob[cell];
                }
            }
            for (int i = 0; i < num; ++i) {
                float4 p = spos[base + i];          // base is global (includes batch offset)
                float d = pdist4(qx, qy, qz, qxx, p.x, p.y, p.z);
                int oi = __float_as_int(p.w);
                unsigned long long key = ((unsigned long long)fkey(d) << 27)
                                       | ((unsigned long long)(unsigned)oi << 14)
                                       | (unsigned)(base + i);
                if (key < a[15]) {
                    a[15] = key;
                    #pragma unroll
                    for (int t2 = 15; t2 > 0; --t2) {
                        unsigned long long lo = (a[t2 - 1] < a[t2]) ? a[t2 - 1] : a[t2];
                        unsigned long long hi = (a[t2 - 1] < a[t2]) ? a[t2] : a[t2 - 1];
                        a[t2 - 1] = lo; a[t2] = hi;
                    }
                }
            }
        }
        // stop: >=16 candidates strictly inside the exact box-face margin.
        // Shells 0..R = full box [c-R,c+R]^3 (grid-clamped). Any unscanned point is in
        // a cell outside the box, hence beyond an (unclamped) face plane in some axis
        // (points clamped into border cells are inside the box or beyond the plane).
        float mlx = qx - (ORGN + (float)(cx - R) * HCELL);
        float mhx = (ORGN + (float)(cx + R + 1) * HCELL) - qx;
        float mly = qy - (ORGN + (float)(cy - R) * HCELL);
        float mhy = (ORGN + (float)(cy + R + 1) * HCELL) - qy;
        float mlz = qz - (ORGN + (float)(cz - R) * HCELL);
        float mhz = (ORGN + (float)(cz + R + 1) * HCELL) - qz;
        float margin = fminf(fminf(fminf(mlx, mhx), fminf(mly, mhy)), fminf(mlz, mhz));
        float thr = margin * margin - 1e-4f;   // shave covers fp cancellation in pdist4
        unsigned long long tkey = ((unsigned long long)(fkey(thr) + 1u)) << 27;
        int c = 0;
        #pragma unroll
        for (int i = 0; i < 16; ++i) c += (a[i] < tkey) ? 1 : 0;
        for (int o = 32; o > 0; o >>= 1) c += __shfl_xor(c, o, 64);
        if (c >= 16 || R > 59) break;
        ++R;
    }

    // exact global top-16: 16 rounds of wave-wide u64 argmin over sorted heads
    unsigned long long keep = ~0ULL;
    for (int k = 0; k < 16; ++k) {
        unsigned long long m = a[0];
        for (int o = 32; o > 0; o >>= 1) {
            unsigned long long pv = shflx64(m, o);
            m = (pv < m) ? pv : m;
        }
        unsigned long long bal = __ballot(a[0] == m);
        int wl = __ffsll((long long)bal) - 1;
        if (lane == wl) {
            #pragma unroll
            for (int i = 0; i < 15; ++i) a[i] = a[i + 1];
            a[15] = ~0ULL;
        }
        if (lane == k) keep = m;
    }

    float rx = 0.f, ry = 0.f, rz = 0.f, rd = 0.f;
    if (lane < 16) {
        int sp = (int)(keep & 0x3FFFu);
        int oi = (int)((keep >> 14) & 0x1FFFu);
        float4 p = spos[sp];
        rx = p.x - qx; ry = p.y - qy; rz = p.z - qz;
        rd = sqrtf(__fadd_rn(__fadd_rn(__fmul_rn(rx, rx), __fmul_rn(ry, ry)), __fmul_rn(rz, rz)));
        knn[(((size_t)b << 13) + nq) * 16 + lane] = oi;
    }
    for (int o = 8; o > 0; o >>= 1) {
        rx += __shfl_xor(rx, o, 64);
        ry += __shfl_xor(ry, o, 64);
        rz += __shfl_xor(rz, o, 64);
        rd += __shfl_xor(rd, o, 64);
    }
    if (lane == 0) {
        const float inv16 = 0.0625f;
        spatial[((size_t)b * 4 + 0) * NPTS + nq] = rx * inv16;
        spatial[((size_t)b * 4 + 1) * NPTS + nq] = ry * inv16;
        spatial[((size_t)b * 4 + 2) * NPTS + nq] = rz * inv16;
        spatial[((size_t)b * 4 + 3) * NPTS + nq] = rd * inv16;
    }
}

// ---------------- x[B,C,N] -> xT[B,N,C] ----------------
__global__ void transpose_k(const float* __restrict__ x, float* __restrict__ xT) {
    __shared__ float tl[32][33];
    int b = blockIdx.z;
    int n0 = blockIdx.x * 32, c0 = blockIdx.y * 32;
    int tx = threadIdx.x, ty = threadIdx.y;
    const float* xb = x + (size_t)b * 128 * NN;
    float* xtb = xT + (size_t)b * NN * 128;
    for (int i = 0; i < 32; i += 8) tl[ty + i][tx] = xb[(size_t)(c0 + ty + i) * NN + n0 + tx];
    __syncthreads();
    for (int i = 0; i < 32; i += 8) xtb[(size_t)(n0 + ty + i) * 128 + c0 + tx] = tl[tx][ty + i];
}

// ---------------- max_k(x[:,idx_k]) - x  -> md[B,128,N] ----------------
__global__ __launch_bounds__(256) void md_k(const float* __restrict__ xT,
                                            const int* __restrict__ knn,
                                            float* __restrict__ md) {
    __shared__ int ki[8][16];
    __shared__ float smd[8][132];
    int b = blockIdx.y;
    int n0 = blockIdx.x * 8;
    int tid = threadIdx.x;
    if (tid < 128) ki[tid >> 4][tid & 15] = knn[(((size_t)b << 13) + n0 + (tid >> 4)) * 16 + (tid & 15)];
    __syncthreads();
    int nl = tid >> 5;
    int c4 = (tid & 31) * 4;
    const float* xb = xT + (size_t)b * NPTS * 128;
    float4 m = make_float4(-3.0e38f, -3.0e38f, -3.0e38f, -3.0e38f);
    #pragma unroll
    for (int k = 0; k < 16; ++k) {
        const float4 g = *(const float4*)(xb + (size_t)ki[nl][k] * 128 + c4);
        m.x = fmaxf(m.x, g.x); m.y = fmaxf(m.y, g.y); m.z = fmaxf(m.z, g.z); m.w = fmaxf(m.w, g.w);
    }
    const float4 own = *(const float4*)(xb + (size_t)(n0 + nl) * 128 + c4);
    m.x -= own.x; m.y -= own.y; m.z -= own.z; m.w -= own.w;
    *(float4*)(&smd[nl][c4]) = m;
    __syncthreads();
    for (int r = 0; r < 4; ++r) {
        int c = (tid >> 3) + 32 * r;
        int n2 = tid & 7;
        md[((size_t)b * 128 + c) * NN + n0 + n2] = smd[n2][c];
    }
}

// ---------------- fold conv-bias + BN into per-channel scale/shift ----------------
__global__ void prep_k(const float* bb1, const float* g1, const float* be1, const float* m1, const float* v1,
                       const float* bb2, const float* g2, const float* be2, const float* m2, const float* v2,
                       const float* sb1, const float* gs,  const float* bes, const float* ms, const float* vs,
                       const float* sb2,
                       const float* ab1, const float* ga,  const float* bea, const float* ma, const float* va,
                       const float* ab2, float* sc) {
    int t = threadIdx.x;
    if (t < 128) {
        float i1 = g1[t] / sqrtf(v1[t] + 1e-5f);
        sc[t] = i1;        sc[128 + t] = bb1[t] * i1 + be1[t] - m1[t] * i1;
        float i2 = g2[t] / sqrtf(v2[t] + 1e-5f);
        sc[256 + t] = i2;  sc[384 + t] = bb2[t] * i2 + be2[t] - m2[t] * i2;
        sc[832 + t] = 1.0f; sc[960 + t] = ab2[t];
    }
    if (t < 32) {
        float is = gs[t] / sqrtf(vs[t] + 1e-5f);
        sc[512 + t] = is;  sc[544 + t] = sb1[t] * is + bes[t] - ms[t] * is;
    }
    if (t < 64) {
        sc[576 + t] = 1.0f; sc[640 + t] = sb2[t];
        float ia = ga[t] / sqrtf(va[t] + 1e-5f);
        sc[704 + t] = ia;  sc[768 + t] = ab1[t] * ia + bea[t] - ma[t] * ia;
    }
}

// ---------------- generic 1x1-conv (+folded BN, activation) ----------------
// ACT: 0=none, 1=relu, 2=sigmoid + fused "dout = x + y2*attn"
template <int O, int K, int TILE_N, int SPLIT, int ACT>
__global__ __launch_bounds__(256) void conv_bn(const float* __restrict__ srcA,
                                               const float* __restrict__ srcB,
                                               const float* __restrict__ W,
                                               const float* __restrict__ scale,
                                               const float* __restrict__ shift,
                                               float* __restrict__ out,
                                               const float* __restrict__ resx,
                                               const float* __restrict__ y2,
                                               float* __restrict__ dout) {
    constexpr int KC  = (K < 64) ? K : 64;
    constexpr int NT4 = TILE_N / 4;
    constexpr int O4  = O / 4;
    static_assert(NT4 * O4 == 256, "thread mapping");
    __shared__ float wT[KC][O + 4];
    __shared__ float inT[KC][TILE_N];
    int tid = threadIdx.x;
    int b = blockIdx.z;
    int n0 = blockIdx.x * TILE_N;
    int n_thr = tid % NT4;          // n fastest -> coalesced stores
    int o_thr = tid / NT4;
    float acc[4][4] = {{0.f, 0.f, 0.f, 0.f}, {0.f, 0.f, 0.f, 0.f}, {0.f, 0.f, 0.f, 0.f}, {0.f, 0.f, 0.f, 0.f}};

    for (int k0 = 0; k0 < K; k0 += KC) {
        for (int idx = tid; idx < KC * O; idx += 256) {
            int cc = idx % KC;
            int o  = idx / KC;
            wT[cc][o] = W[(size_t)o * K + k0 + cc];
        }
        for (int idx = tid; idx < KC * NT4; idx += 256) {
            int cc = idx / NT4;
            int nf = idx % NT4;
            int cg = k0 + cc;
            const float* src = (cg < SPLIT)
                ? (srcA + ((size_t)b * SPLIT + cg) * NN)
                : (srcB + ((size_t)b * (K - SPLIT) + (cg - SPLIT)) * NN);
            *(float4*)(&inT[cc][nf * 4]) = *(const float4*)(src + n0 + nf * 4);
        }
        __syncthreads();
        #pragma unroll 8
        for (int c = 0; c < KC; ++c) {
            float4 wv = *(const float4*)(&wT[c][o_thr * 4]);
            float4 iv = *(const float4*)(&inT[c][n_thr * 4]);
            acc[0][0] = fmaf(wv.x, iv.x, acc[0][0]); acc[0][1] = fmaf(wv.x, iv.y, acc[0][1]);
            acc[0][2] = fmaf(wv.x, iv.z, acc[0][2]); acc[0][3] = fmaf(wv.x, iv.w, acc[0][3]);
            acc[1][0] = fmaf(wv.y, iv.x, acc[1][0]); acc[1][1] = fmaf(wv.y, iv.y, acc[1][1]);
            acc[1][2] = fmaf(wv.y, iv.z, acc[1][2]); acc[1][3] = fmaf(wv.y, iv.w, acc[1][3]);
            acc[2][0] = fmaf(wv.z, iv.x, acc[2][0]); acc[2][1] = fmaf(wv.z, iv.y, acc[2][1]);
            acc[2][2] = fmaf(wv.z, iv.z, acc[2][2]); acc[2][3] = fmaf(wv.z, iv.w, acc[2][3]);
            acc[3][0] = fmaf(wv.w, iv.x, acc[3][0]); acc[3][1] = fmaf(wv.w, iv.y, acc[3][1]);
            acc[3][2] = fmaf(wv.w, iv.z, acc[3][2]); acc[3][3] = fmaf(wv.w, iv.w, acc[3][3]);
        }
        __syncthreads();
    }
    #pragma unroll
    for (int j = 0; j < 4; ++j) {
        int o = o_thr * 4 + j;
        float scv = scale[o], shv = shift[o];
        float4 v;
        v.x = fmaf(acc[j][0], scv, shv);
        v.y = fmaf(acc[j][1], scv, shv);
        v.z = fmaf(acc[j][2], scv, shv);
        v.w = fmaf(acc[j][3], scv, shv);
        size_t obase = ((size_t)b * O + o) * NN + n0 + n_thr * 4;
        if (ACT == 1) {
            v.x = fmaxf(v.x, 0.f); v.y = fmaxf(v.y, 0.f); v.z = fmaxf(v.z, 0.f); v.w = fmaxf(v.w, 0.f);
            *(float4*)(out + obase) = v;
        } else if (ACT == 2) {
            float4 xr = *(const float4*)(resx + obase);
            float4 yr = *(const float4*)(y2 + obase);
            v.x = xr.x + yr.x / (1.f + __expf(-v.x));
            v.y = xr.y + yr.y / (1.f + __expf(-v.y));
            v.z = xr.z + yr.z / (1.f + __expf(-v.z));
            v.w = xr.w + yr.w / (1.f + __expf(-v.w));
            *(float4*)(dout + obase) = v;
        } else {
            *(float4*)(out + obase) = v;
        }
    }
}

extern "C" void kernel_launch(void* const* d_in, const int* in_sizes, int n_in,
                              void* d_out, int out_size, void* d_ws, size_t ws_size,
                              hipStream_t stream) {
    (void)in_sizes; (void)n_in; (void)out_size; (void)ws_size;
    const float* x    = (const float*)d_in[0];
    const float* xyz  = (const float*)d_in[1];
    const float* bw1  = (const float*)d_in[2];
    const float* bb1  = (const float*)d_in[3];
    const float* bn1g = (const float*)d_in[4];
    const float* bn1b = (const float*)d_in[5];
    const float* bn1m = (const float*)d_in[6];
    const float* bn1v = (const float*)d_in[7];
    const float* bw2  = (const float*)d_in[8];
    const float* bb2  = (const float*)d_in[9];
    const float* bn2g = (const float*)d_in[10];
    const float* bn2b = (const float*)d_in[11];
    const float* bn2m = (const float*)d_in[12];
    const float* bn2v = (const float*)d_in[13];
    const float* sw1  = (const float*)d_in[14];
    const float* sb1  = (const float*)d_in[15];
    const float* sbng = (const float*)d_in[16];
    const float* sbnb = (const float*)d_in[17];
    const float* sbnm = (const float*)d_in[18];
    const float* sbnv = (const float*)d_in[19];
    const float* sw2  = (const float*)d_in[20];
    const float* sb2  = (const float*)d_in[21];
    const float* aw1  = (const float*)d_in[22];
    const float* ab1  = (const float*)d_in[23];
    const float* abng = (const float*)d_in[24];
    const float* abnb = (const float*)d_in[25];
    const float* abnm = (const float*)d_in[26];
    const float* abnv = (const float*)d_in[27];
    const float* aw2  = (const float*)d_in[28];
    const float* ab2  = (const float*)d_in[29];

    char* ws = (char*)d_ws;
    int*    cnt    = (int*)(ws + OFF_CNT);
    int*    offs   = (int*)(ws + OFF_OFFS);
    int*    cellid = (int*)(ws + OFF_CELLID);
    int*    rank   = (int*)(ws + OFF_RANK);
    float4* spos   = (float4*)(ws + OFF_SPOS);
    int*    knn    = (int*)(ws + OFF_KNN);
    float*  spat   = (float*)(ws + OFF_SPATIAL);
    float*  xT     = (float*)(ws + OFF_XT);
    float*  md     = (float*)(ws + OFF_MD);
    float*  s1b    = (float*)(ws + OFF_S1);
    float*  sfb    = (float*)(ws + OFF_SF);
    float*  y1b    = (float*)(ws + OFF_Y1);
    float*  y2b    = (float*)(ws + OFF_Y2);
    float*  a1b    = (float*)(ws + OFF_A1);
    float*  sc     = (float*)(ws + OFF_SC);
    int*    bsum   = (int*)(ws + OFF_BSUM);
    int*    bpre   = (int*)(ws + OFF_BPRE);
    float*  dout   = (float*)d_out;

    hipMemsetAsync(cnt, 0, (size_t)TOTC * 4, stream);
    cell_build<<<dim3((NTOT + 255) / 256), 256, 0, stream>>>(xyz, cnt, cellid, rank);
    scan_sums<<<dim3(NBLK_SCAN), 256, 0, stream>>>(cnt, bsum);
    scan_top<<<dim3(1), 512, 0, stream>>>(bsum, bpre);
    scan_write<<<dim3(NBLK_SCAN), 256, 0, stream>>>(cnt, bpre, offs);
    scatter_k<<<dim3((NTOT + 255) / 256), 256, 0, stream>>>(xyz, cellid, rank, offs, spos);
    knn_kernel<<<dim3(NTOT / 4), 256, 0, stream>>>(spos, cnt, offs, knn, spat);
    transpose_k<<<dim3(NPTS / 32, 128 / 32, NB), dim3(32, 8), 0, stream>>>(x, xT);
    md_k<<<dim3(NPTS / 8, NB), 256, 0, stream>>>(xT, knn, md);
    prep_k<<<1, 128, 0, stream>>>(bb1, bn1g, bn1b, bn1m, bn1v,
                                  bb2, bn2g, bn2b, bn2m, bn2v,
                                  sb1, sbng, sbnb, sbnm, sbnv,
                                  sb2,
                                  ab1, abng, abnb, abnm, abnv,
                                  ab2, sc);
    // spatial MLP: 4->32 (bn,relu), 32->64
    conv_bn<32, 4, 128, 4, 1><<<dim3(NPTS / 128, 1, NB), 256, 0, stream>>>(
        spat, spat, sw1, sc + 512, sc + 544, s1b, nullptr, nullptr, nullptr);
    conv_bn<64, 32, 64, 32, 0><<<dim3(NPTS / 64, 1, NB), 256, 0, stream>>>(
        s1b, s1b, sw2, sc + 576, sc + 640, sfb, nullptr, nullptr, nullptr);
    // boundary net: [x;md] 256->128 (bn,relu), 128->128 (bn,relu)
    conv_bn<128, 256, 32, 128, 1><<<dim3(NPTS / 32, 1, NB), 256, 0, stream>>>(
        x, md, bw1, sc + 0, sc + 128, y1b, nullptr, nullptr, nullptr);
    conv_bn<128, 128, 32, 128, 1><<<dim3(NPTS / 32, 1, NB), 256, 0, stream>>>(
        y1b, y1b, bw2, sc + 256, sc + 384, y2b, nullptr, nullptr, nullptr);
    // attention: [x;sfeat] 192->64 (bn,relu), 64->128 sigmoid + final fuse
    conv_bn<64, 192, 64, 128, 1><<<dim3(NPTS / 64, 1, NB), 256, 0, stream>>>(
        x, sfb, aw1, sc + 704, sc + 768, a1b, nullptr, nullptr, nullptr);
    conv_bn<128, 64, 32, 64, 2><<<dim3(NPTS / 32, 1, NB), 256, 0, stream>>>(
        a1b, a1b, aw2, sc + 832, sc + 960, dout, x, y2b, dout);
}

// Round 6
// 453.211 us; speedup vs baseline: 12.8781x; 1.0312x over previous
//
#include <hip/hip_runtime.h>
#include <math.h>

#define NPTS  8192
#define NB    2
#define NTOT  (NPTS*NB)
#define GD    60
#define NCELL (GD*GD*GD)
#define TOTC  (NB*NCELL)
#define HCELL 0.2f
#define INVH  5.0f
#define ORGN  (-6.0f)
#define NN    8192
#define SCAN_CHUNK 1024
#define NBLK_SCAN  ((TOTC + SCAN_CHUNK - 1) / SCAN_CHUNK)

// ---------------- workspace layout (bytes) ----------------
#define OFF_CNT     ((size_t)0)
#define OFF_OFFS    (OFF_CNT    + (size_t)TOTC*4)
#define OFF_CELLID  (OFF_OFFS   + (size_t)TOTC*4)
#define OFF_RANK    (OFF_CELLID + (size_t)NTOT*4)
#define OFF_SPOS    (OFF_RANK   + (size_t)NTOT*4)          // float4 * NTOT (w = origidx bits)
#define OFF_KNN     (OFF_SPOS   + (size_t)NTOT*16)         // int * NTOT*16
#define OFF_SPATIAL (OFF_KNN    + (size_t)NTOT*16*4)       // [B,4,N]
#define OFF_XT      (OFF_SPATIAL+ (size_t)NB*4*NPTS*4)     // [B,N,128]
#define OFF_MD      (OFF_XT     + (size_t)NB*128*NPTS*4)   // [B,128,N]
#define OFF_S1      (OFF_MD     + (size_t)NB*128*NPTS*4)   // [B,32,N]
#define OFF_SF      (OFF_S1     + (size_t)NB*32*NPTS*4)    // [B,64,N]
#define OFF_Y1      (OFF_SF     + (size_t)NB*64*NPTS*4)    // [B,128,N]
#define OFF_Y2      (OFF_Y1     + (size_t)NB*128*NPTS*4)   // [B,128,N]
#define OFF_A1      (OFF_Y2     + (size_t)NB*128*NPTS*4)   // [B,64,N]
#define OFF_SC      (OFF_A1     + (size_t)NB*64*NPTS*4)    // 1088 floats
#define OFF_BSUM    (OFF_SC     + (size_t)1088*4)          // NBLK_SCAN ints
#define OFF_BPRE    (OFF_BSUM   + (size_t)NBLK_SCAN*4)     // NBLK_SCAN ints

// Replicate reference arithmetic exactly (no fma contraction).
static __device__ __forceinline__ float sumsq3(float x, float y, float z) {
    return __fadd_rn(__fadd_rn(__fmul_rn(x, x), __fmul_rn(y, y)), __fmul_rn(z, z));
}
static __device__ __forceinline__ float pdist4(float qx, float qy, float qz, float qxx,
                                               float px, float py, float pz) {
    float pxx = sumsq3(px, py, pz);
    float dot = __fadd_rn(__fadd_rn(__fmul_rn(qx, px), __fmul_rn(qy, py)), __fmul_rn(qz, pz));
    return __fsub_rn(__fadd_rn(qxx, pxx), __fadd_rn(dot, dot));
}
// monotone unsigned key for float (handles tiny negative self-distance)
static __device__ __forceinline__ unsigned fkey(float f) {
    unsigned b = __float_as_uint(f);
    return b ^ ((unsigned)(((int)b) >> 31) | 0x80000000u);
}
static __device__ __forceinline__ unsigned long long shflx64(unsigned long long v, int m) {
    unsigned lo = __shfl_xor((unsigned)v, m, 64);
    unsigned hi = __shfl_xor((unsigned)(v >> 32), m, 64);
    return ((unsigned long long)hi << 32) | lo;
}

// ---------------- grid build ----------------
__global__ void cell_build(const float* __restrict__ xyz, int* __restrict__ cnt,
                           int* __restrict__ cellid, int* __restrict__ rank) {
    int t = blockIdx.x * 256 + threadIdx.x;
    if (t >= NTOT) return;
    const float* p = xyz + (size_t)t * 3;
    float x = p[0], y = p[1], z = p[2];
    int cx = min(GD - 1, max(0, (int)floorf((x - ORGN) * INVH)));
    int cy = min(GD - 1, max(0, (int)floorf((y - ORGN) * INVH)));
    int cz = min(GD - 1, max(0, (int)floorf((z - ORGN) * INVH)));
    int gcell = (t >> 13) * NCELL + (cz * GD + cy) * GD + cx;
    rank[t] = atomicAdd(&cnt[gcell], 1);
    cellid[t] = gcell;
}

// -------- hierarchical exclusive scan of cnt[TOTC] -> offs[TOTC] --------
__global__ __launch_bounds__(256) void scan_sums(const int* __restrict__ cnt, int* __restrict__ bsum) {
    __shared__ int red[256];
    int blk = blockIdx.x, t = threadIdx.x;
    int i0 = blk * SCAN_CHUNK + t * 4;
    int s = 0;
    if (i0 + 3 < TOTC) {
        int4 v = *(const int4*)(cnt + i0);
        s = v.x + v.y + v.z + v.w;
    } else {
        for (int j = 0; j < 4; ++j) if (i0 + j < TOTC) s += cnt[i0 + j];
    }
    red[t] = s;
    __syncthreads();
    for (int d = 128; d > 0; d >>= 1) {
        if (t < d) red[t] += red[t + d];
        __syncthreads();
    }
    if (t == 0) bsum[blk] = red[0];
}

__global__ __launch_bounds__(512) void scan_top(const int* __restrict__ bsum, int* __restrict__ bpre) {
    __shared__ int ps[512];
    int t = threadIdx.x;
    int v = (t < NBLK_SCAN) ? bsum[t] : 0;
    ps[t] = v;
    __syncthreads();
    for (int d = 1; d < 512; d <<= 1) {
        int u = 0;
        if (t >= d) u = ps[t - d];
        __syncthreads();
        ps[t] += u;
        __syncthreads();
    }
    if (t < NBLK_SCAN) bpre[t] = ps[t] - v;   // exclusive
}

__global__ __launch_bounds__(256) void scan_write(const int* __restrict__ cnt, const int* __restrict__ bpre,
                                                  int* __restrict__ offs) {
    __shared__ int ps[256];
    int blk = blockIdx.x, t = threadIdx.x;
    int i0 = blk * SCAN_CHUNK + t * 4;
    int a = 0, b = 0, c = 0, d = 0;
    if (i0 + 3 < TOTC) {
        int4 v = *(const int4*)(cnt + i0);
        a = v.x; b = v.y; c = v.z; d = v.w;
    } else {
        if (i0 + 0 < TOTC) a = cnt[i0 + 0];
        if (i0 + 1 < TOTC) b = cnt[i0 + 1];
        if (i0 + 2 < TOTC) c = cnt[i0 + 2];
        if (i0 + 3 < TOTC) d = cnt[i0 + 3];
    }
    int s = a + b + c + d;
    ps[t] = s;
    __syncthreads();
    for (int dd = 1; dd < 256; dd <<= 1) {
        int u = 0;
        if (t >= dd) u = ps[t - dd];
        __syncthreads();
        ps[t] += u;
        __syncthreads();
    }
    int base = bpre[blk] + ps[t] - s;
    if (i0 + 0 < TOTC) offs[i0 + 0] = base;
    if (i0 + 1 < TOTC) offs[i0 + 1] = base + a;
    if (i0 + 2 < TOTC) offs[i0 + 2] = base + a + b;
    if (i0 + 3 < TOTC) offs[i0 + 3] = base + a + b + c;
}

__global__ void scatter_k(const float* __restrict__ xyz, const int* __restrict__ cellid,
                          const int* __restrict__ rank, const int* __restrict__ offs,
                          float4* __restrict__ spos) {
    int t = blockIdx.x * 256 + threadIdx.x;
    if (t >= NTOT) return;
    const float* p = xyz + (size_t)t * 3;
    float x = p[0], y = p[1], z = p[2];
    int pos = offs[cellid[t]] + rank[t];
    spos[pos] = make_float4(x, y, z, __int_as_float(t & (NPTS - 1)));
}

// decode u-th cell of Chebyshev shell R (R>=1); S(R)=24R^2+2
static __device__ __forceinline__ void shell_decode(int R, int u, int& dx, int& dy, int& dz) {
    int L = 2 * R + 1, P = L * L;
    if (u < 2 * P) {
        int v = (u < P) ? u : u - P;
        dz = (u < P) ? -R : R;
        dx = v % L - R;
        dy = v / L - R;
    } else {
        int w = u - 2 * P;
        int ring = w / (8 * R);
        int p = w - ring * 8 * R;
        dz = ring - (R - 1);
        if (p < 2 * R)      { dx = p - R;            dy = -R; }
        else if (p < 4 * R) { dx = R;                dy = p - 3 * R; }
        else if (p < 6 * R) { dx = 5 * R - p;        dy = R; }
        else                { dx = -R;               dy = 7 * R - p; }
    }
}

// ---------------- exact KNN: one wave per query ----------------
// R6 change (only the candidate bookkeeping; shells/stop/epilogue = R5 verbatim):
// per-lane UNSORTED top-16 buffer in LDS (layout [wave][j][lane] -> lane-consecutive,
// conflict-light) with register-cached minkey/maxkey. Insert = 1 ds_write + min/max
// update (vs ~130-inst AGPR-resident sorted bubble). Exactness: per-lane "16 smallest
// seen with drop-max" union contains the global top-16; stop-count over the union is
// unaffected by drops (a dropped key < tkey implies 16 better keys on that lane).
__global__ __launch_bounds__(256, 4) void knn_kernel(const float4* __restrict__ spos,
                                                     const int* __restrict__ cnt,
                                                     const int* __restrict__ offs,
                                                     int* __restrict__ knn,
                                                     float* __restrict__ spatial) {
    __shared__ unsigned long long buf[4][16][64];
    int lane = threadIdx.x & 63;
    int wv   = threadIdx.x >> 6;
    int s    = blockIdx.x * 4 + wv;       // query slot in sorted order
    float4 q = spos[s];
    float qx = q.x, qy = q.y, qz = q.z;
    float qxx = sumsq3(qx, qy, qz);
    int b  = s >> 13;
    int nq = __float_as_int(q.w);
    int cx = min(GD - 1, max(0, (int)floorf((qx - ORGN) * INVH)));
    int cy = min(GD - 1, max(0, (int)floorf((qy - ORGN) * INVH)));
    int cz = min(GD - 1, max(0, (int)floorf((qz - ORGN) * INVH)));
    const int* cb = cnt  + b * NCELL;
    const int* ob = offs + b * NCELL;     // offs is a GLOBAL scan; base below is a global slot

    unsigned long long* mybuf = &buf[wv][0][lane];   // element j at mybuf[j*64]
    unsigned long long minkey = ~0ULL;
    unsigned long long maxkey = 0;
    int nbuf = 0;

    int R = 0;
    while (true) {
        int S = (R == 0) ? 1 : 24 * R * R + 2;
        for (int u0 = 0; u0 < S; u0 += 64) {
            int u = u0 + lane;
            int num = 0, base = 0;
            if (u < S) {
                int dx = 0, dy = 0, dz = 0;
                if (R > 0) shell_decode(R, u, dx, dy, dz);
                int xc = cx + dx, yc = cy + dy, zc = cz + dz;
                if ((unsigned)xc < GD && (unsigned)yc < GD && (unsigned)zc < GD) {
                    int cell = (zc * GD + yc) * GD + xc;
                    num  = cb[cell];
                    base = ob[cell];
                }
            }
            for (int i = 0; i < num; ++i) {
                float4 p = spos[base + i];          // base is global (includes batch offset)
                float d = pdist4(qx, qy, qz, qxx, p.x, p.y, p.z);
                int oi = __float_as_int(p.w);
                unsigned long long key = ((unsigned long long)fkey(d) << 27)
                                       | ((unsigned long long)(unsigned)oi << 14)
                                       | (unsigned)(base + i);
                if (nbuf < 16) {
                    mybuf[(size_t)nbuf * 64] = key;
                    ++nbuf;
                    minkey = (key < minkey) ? key : minkey;
                    maxkey = (key > maxkey) ? key : maxkey;
                } else if (key < maxkey) {
                    // rare: buffer full — replace current max, keep 16 smallest
                    unsigned long long vmax = 0, v2 = 0;
                    int pmax = 0;
                    #pragma unroll
                    for (int j = 0; j < 16; ++j) {
                        unsigned long long v = mybuf[(size_t)j * 64];
                        if (v > vmax) { v2 = vmax; vmax = v; pmax = j; }
                        else if (v > v2) { v2 = v; }
                    }
                    mybuf[(size_t)pmax * 64] = key;
                    maxkey = (key > v2) ? key : v2;
                    minkey = (key < minkey) ? key : minkey;
                }
            }
        }
        // stop: >=16 candidates strictly inside the exact box-face margin (R5-proven).
        float mlx = qx - (ORGN + (float)(cx - R) * HCELL);
        float mhx = (ORGN + (float)(cx + R + 1) * HCELL) - qx;
        float mly = qy - (ORGN + (float)(cy - R) * HCELL);
        float mhy = (ORGN + (float)(cy + R + 1) * HCELL) - qy;
        float mlz = qz - (ORGN + (float)(cz - R) * HCELL);
        float mhz = (ORGN + (float)(cz + R + 1) * HCELL) - qz;
        float margin = fminf(fminf(fminf(mlx, mhx), fminf(mly, mhy)), fminf(mlz, mhz));
        float thr = margin * margin - 1e-4f;   // shave covers fp cancellation in pdist4
        unsigned long long tkey = ((unsigned long long)(fkey(thr) + 1u)) << 27;
        int c = 0;
        for (int j = 0; j < nbuf; ++j) c += (mybuf[(size_t)j * 64] < tkey) ? 1 : 0;
        for (int o = 32; o > 0; o >>= 1) c += __shfl_xor(c, o, 64);
        if (c >= 16 || R > 59) break;
        ++R;
    }

    // exact global top-16: 16 rounds of wave-wide u64 argmin over cached lane minima
    unsigned long long keep = ~0ULL;
    for (int k = 0; k < 16; ++k) {
        unsigned long long m = minkey;
        for (int o = 32; o > 0; o >>= 1) {
            unsigned long long pv = shflx64(m, o);
            m = (pv < m) ? pv : m;
        }
        unsigned long long bal = __ballot(minkey == m);
        int wl = __ffsll((long long)bal) - 1;
        if (lane == wl) {
            int pos = 0;
            for (int j = 0; j < nbuf; ++j) if (mybuf[(size_t)j * 64] == m) pos = j;
            --nbuf;
            mybuf[(size_t)pos * 64] = mybuf[(size_t)nbuf * 64];
            unsigned long long nm = ~0ULL;
            for (int j = 0; j < nbuf; ++j) {
                unsigned long long v = mybuf[(size_t)j * 64];
                nm = (v < nm) ? v : nm;
            }
            minkey = nm;
        }
        if (lane == k) keep = m;
    }

    float rx = 0.f, ry = 0.f, rz = 0.f, rd = 0.f;
    if (lane < 16) {
        int sp = (int)(keep & 0x3FFFu);
        int oi = (int)((keep >> 14) & 0x1FFFu);
        float4 p = spos[sp];
        rx = p.x - qx; ry = p.y - qy; rz = p.z - qz;
        rd = sqrtf(__fadd_rn(__fadd_rn(__fmul_rn(rx, rx), __fmul_rn(ry, ry)), __fmul_rn(rz, rz)));
        knn[(((size_t)b << 13) + nq) * 16 + lane] = oi;
    }
    for (int o = 8; o > 0; o >>= 1) {
        rx += __shfl_xor(rx, o, 64);
        ry += __shfl_xor(ry, o, 64);
        rz += __shfl_xor(rz, o, 64);
        rd += __shfl_xor(rd, o, 64);
    }
    if (lane == 0) {
        const float inv16 = 0.0625f;
        spatial[((size_t)b * 4 + 0) * NPTS + nq] = rx * inv16;
        spatial[((size_t)b * 4 + 1) * NPTS + nq] = ry * inv16;
        spatial[((size_t)b * 4 + 2) * NPTS + nq] = rz * inv16;
        spatial[((size_t)b * 4 + 3) * NPTS + nq] = rd * inv16;
    }
}

// ---------------- x[B,C,N] -> xT[B,N,C] ----------------
__global__ void transpose_k(const float* __restrict__ x, float* __restrict__ xT) {
    __shared__ float tl[32][33];
    int b = blockIdx.z;
    int n0 = blockIdx.x * 32, c0 = blockIdx.y * 32;
    int tx = threadIdx.x, ty = threadIdx.y;
    const float* xb = x + (size_t)b * 128 * NN;
    float* xtb = xT + (size_t)b * NN * 128;
    for (int i = 0; i < 32; i += 8) tl[ty + i][tx] = xb[(size_t)(c0 + ty + i) * NN + n0 + tx];
    __syncthreads();
    for (int i = 0; i < 32; i += 8) xtb[(size_t)(n0 + ty + i) * 128 + c0 + tx] = tl[tx][ty + i];
}

// ---------------- max_k(x[:,idx_k]) - x  -> md[B,128,N] ----------------
__global__ __launch_bounds__(256) void md_k(const float* __restrict__ xT,
                                            const int* __restrict__ knn,
                                            float* __restrict__ md) {
    __shared__ int ki[8][16];
    __shared__ float smd[8][132];
    int b = blockIdx.y;
    int n0 = blockIdx.x * 8;
    int tid = threadIdx.x;
    if (tid < 128) ki[tid >> 4][tid & 15] = knn[(((size_t)b << 13) + n0 + (tid >> 4)) * 16 + (tid & 15)];
    __syncthreads();
    int nl = tid >> 5;
    int c4 = (tid & 31) * 4;
    const float* xb = xT + (size_t)b * NPTS * 128;
    float4 m = make_float4(-3.0e38f, -3.0e38f, -3.0e38f, -3.0e38f);
    #pragma unroll
    for (int k = 0; k < 16; ++k) {
        const float4 g = *(const float4*)(xb + (size_t)ki[nl][k] * 128 + c4);
        m.x = fmaxf(m.x, g.x); m.y = fmaxf(m.y, g.y); m.z = fmaxf(m.z, g.z); m.w = fmaxf(m.w, g.w);
    }
    const float4 own = *(const float4*)(xb + (size_t)(n0 + nl) * 128 + c4);
    m.x -= own.x; m.y -= own.y; m.z -= own.z; m.w -= own.w;
    *(float4*)(&smd[nl][c4]) = m;
    __syncthreads();
    for (int r = 0; r < 4; ++r) {
        int c = (tid >> 3) + 32 * r;
        int n2 = tid & 7;
        md[((size_t)b * 128 + c) * NN + n0 + n2] = smd[n2][c];
    }
}

// ---------------- fold conv-bias + BN into per-channel scale/shift ----------------
__global__ void prep_k(const float* bb1, const float* g1, const float* be1, const float* m1, const float* v1,
                       const float* bb2, const float* g2, const float* be2, const float* m2, const float* v2,
                       const float* sb1, const float* gs,  const float* bes, const float* ms, const float* vs,
                       const float* sb2,
                       const float* ab1, const float* ga,  const float* bea, const float* ma, const float* va,
                       const float* ab2, float* sc) {
    int t = threadIdx.x;
    if (t < 128) {
        float i1 = g1[t] / sqrtf(v1[t] + 1e-5f);
        sc[t] = i1;        sc[128 + t] = bb1[t] * i1 + be1[t] - m1[t] * i1;
        float i2 = g2[t] / sqrtf(v2[t] + 1e-5f);
        sc[256 + t] = i2;  sc[384 + t] = bb2[t] * i2 + be2[t] - m2[t] * i2;
        sc[832 + t] = 1.0f; sc[960 + t] = ab2[t];
    }
    if (t < 32) {
        float is = gs[t] / sqrtf(vs[t] + 1e-5f);
        sc[512 + t] = is;  sc[544 + t] = sb1[t] * is + bes[t] - ms[t] * is;
    }
    if (t < 64) {
        sc[576 + t] = 1.0f; sc[640 + t] = sb2[t];
        float ia = ga[t] / sqrtf(va[t] + 1e-5f);
        sc[704 + t] = ia;  sc[768 + t] = ab1[t] * ia + bea[t] - ma[t] * ia;
    }
}

// ---------------- generic 1x1-conv (+folded BN, activation) ----------------
// ACT: 0=none, 1=relu, 2=sigmoid + fused "dout = x + y2*attn"
template <int O, int K, int TILE_N, int SPLIT, int ACT>
__global__ __launch_bounds__(256) void conv_bn(const float* __restrict__ srcA,
                                               const float* __restrict__ srcB,
                                               const float* __restrict__ W,
                                               const float* __restrict__ scale,
                                               const float* __restrict__ shift,
                                               float* __restrict__ out,
                                               const float* __restrict__ resx,
                                               const float* __restrict__ y2,
                                               float* __restrict__ dout) {
    constexpr int KC  = (K < 64) ? K : 64;
    constexpr int NT4 = TILE_N / 4;
    constexpr int O4  = O / 4;
    static_assert(NT4 * O4 == 256, "thread mapping");
    __shared__ float wT[KC][O + 4];
    __shared__ float inT[KC][TILE_N];
    int tid = threadIdx.x;
    int b = blockIdx.z;
    int n0 = blockIdx.x * TILE_N;
    int n_thr = tid % NT4;          // n fastest -> coalesced stores
    int o_thr = tid / NT4;
    float acc[4][4] = {{0.f, 0.f, 0.f, 0.f}, {0.f, 0.f, 0.f, 0.f}, {0.f, 0.f, 0.f, 0.f}, {0.f, 0.f, 0.f, 0.f}};

    for (int k0 = 0; k0 < K; k0 += KC) {
        for (int idx = tid; idx < KC * O; idx += 256) {
            int cc = idx % KC;
            int o  = idx / KC;
            wT[cc][o] = W[(size_t)o * K + k0 + cc];
        }
        for (int idx = tid; idx < KC * NT4; idx += 256) {
            int cc = idx / NT4;
            int nf = idx % NT4;
            int cg = k0 + cc;
            const float* src = (cg < SPLIT)
                ? (srcA + ((size_t)b * SPLIT + cg) * NN)
                : (srcB + ((size_t)b * (K - SPLIT) + (cg - SPLIT)) * NN);
            *(float4*)(&inT[cc][nf * 4]) = *(const float4*)(src + n0 + nf * 4);
        }
        __syncthreads();
        #pragma unroll 8
        for (int c = 0; c < KC; ++c) {
            float4 wv = *(const float4*)(&wT[c][o_thr * 4]);
            float4 iv = *(const float4*)(&inT[c][n_thr * 4]);
            acc[0][0] = fmaf(wv.x, iv.x, acc[0][0]); acc[0][1] = fmaf(wv.x, iv.y, acc[0][1]);
            acc[0][2] = fmaf(wv.x, iv.z, acc[0][2]); acc[0][3] = fmaf(wv.x, iv.w, acc[0][3]);
            acc[1][0] = fmaf(wv.y, iv.x, acc[1][0]); acc[1][1] = fmaf(wv.y, iv.y, acc[1][1]);
            acc[1][2] = fmaf(wv.y, iv.z, acc[1][2]); acc[1][3] = fmaf(wv.y, iv.w, acc[1][3]);
            acc[2][0] = fmaf(wv.z, iv.x, acc[2][0]); acc[2][1] = fmaf(wv.z, iv.y, acc[2][1]);
            acc[2][2] = fmaf(wv.z, iv.z, acc[2][2]); acc[2][3] = fmaf(wv.z, iv.w, acc[2][3]);
            acc[3][0] = fmaf(wv.w, iv.x, acc[3][0]); acc[3][1] = fmaf(wv.w, iv.y, acc[3][1]);
            acc[3][2] = fmaf(wv.w, iv.z, acc[3][2]); acc[3][3] = fmaf(wv.w, iv.w, acc[3][3]);
        }
        __syncthreads();
    }
    #pragma unroll
    for (int j = 0; j < 4; ++j) {
        int o = o_thr * 4 + j;
        float scv = scale[o], shv = shift[o];
        float4 v;
        v.x = fmaf(acc[j][0], scv, shv);
        v.y = fmaf(acc[j][1], scv, shv);
        v.z = fmaf(acc[j][2], scv, shv);
        v.w = fmaf(acc[j][3], scv, shv);
        size_t obase = ((size_t)b * O + o) * NN + n0 + n_thr * 4;
        if (ACT == 1) {
            v.x = fmaxf(v.x, 0.f); v.y = fmaxf(v.y, 0.f); v.z = fmaxf(v.z, 0.f); v.w = fmaxf(v.w, 0.f);
            *(float4*)(out + obase) = v;
        } else if (ACT == 2) {
            float4 xr = *(const float4*)(resx + obase);
            float4 yr = *(const float4*)(y2 + obase);
            v.x = xr.x + yr.x / (1.f + __expf(-v.x));
            v.y = xr.y + yr.y / (1.f + __expf(-v.y));
            v.z = xr.z + yr.z / (1.f + __expf(-v.z));
            v.w = xr.w + yr.w / (1.f + __expf(-v.w));
            *(float4*)(dout + obase) = v;
        } else {
            *(float4*)(out + obase) = v;
        }
    }
}

extern "C" void kernel_launch(void* const* d_in, const int* in_sizes, int n_in,
                              void* d_out, int out_size, void* d_ws, size_t ws_size,
                              hipStream_t stream) {
    (void)in_sizes; (void)n_in; (void)out_size; (void)ws_size;
    const float* x    = (const float*)d_in[0];
    const float* xyz  = (const float*)d_in[1];
    const float* bw1  = (const float*)d_in[2];
    const float* bb1  = (const float*)d_in[3];
    const float* bn1g = (const float*)d_in[4];
    const float* bn1b = (const float*)d_in[5];
    const float* bn1m = (const float*)d_in[6];
    const float* bn1v = (const float*)d_in[7];
    const float* bw2  = (const float*)d_in[8];
    const float* bb2  = (const float*)d_in[9];
    const float* bn2g = (const float*)d_in[10];
    const float* bn2b = (const float*)d_in[11];
    const float* bn2m = (const float*)d_in[12];
    const float* bn2v = (const float*)d_in[13];
    const float* sw1  = (const float*)d_in[14];
    const float* sb1  = (const float*)d_in[15];
    const float* sbng = (const float*)d_in[16];
    const float* sbnb = (const float*)d_in[17];
    const float* sbnm = (const float*)d_in[18];
    const float* sbnv = (const float*)d_in[19];
    const float* sw2  = (const float*)d_in[20];
    const float* sb2  = (const float*)d_in[21];
    const float* aw1  = (const float*)d_in[22];
    const float* ab1  = (const float*)d_in[23];
    const float* abng = (const float*)d_in[24];
    const float* abnb = (const float*)d_in[25];
    const float* abnm = (const float*)d_in[26];
    const float* abnv = (const float*)d_in[27];
    const float* aw2  = (const float*)d_in[28];
    const float* ab2  = (const float*)d_in[29];

    char* ws = (char*)d_ws;
    int*    cnt    = (int*)(ws + OFF_CNT);
    int*    offs   = (int*)(ws + OFF_OFFS);
    int*    cellid = (int*)(ws + OFF_CELLID);
    int*    rank   = (int*)(ws + OFF_RANK);
    float4* spos   = (float4*)(ws + OFF_SPOS);
    int*    knn    = (int*)(ws + OFF_KNN);
    float*  spat   = (float*)(ws + OFF_SPATIAL);
    float*  xT     = (float*)(ws + OFF_XT);
    float*  md     = (float*)(ws + OFF_MD);
    float*  s1b    = (float*)(ws + OFF_S1);
    float*  sfb    = (float*)(ws + OFF_SF);
    float*  y1b    = (float*)(ws + OFF_Y1);
    float*  y2b    = (float*)(ws + OFF_Y2);
    float*  a1b    = (float*)(ws + OFF_A1);
    float*  sc     = (float*)(ws + OFF_SC);
    int*    bsum   = (int*)(ws + OFF_BSUM);
    int*    bpre   = (int*)(ws + OFF_BPRE);
    float*  dout   = (float*)d_out;

    hipMemsetAsync(cnt, 0, (size_t)TOTC * 4, stream);
    cell_build<<<dim3((NTOT + 255) / 256), 256, 0, stream>>>(xyz, cnt, cellid, rank);
    scan_sums<<<dim3(NBLK_SCAN), 256, 0, stream>>>(cnt, bsum);
    scan_top<<<dim3(1), 512, 0, stream>>>(bsum, bpre);
    scan_write<<<dim3(NBLK_SCAN), 256, 0, stream>>>(cnt, bpre, offs);
    scatter_k<<<dim3((NTOT + 255) / 256), 256, 0, stream>>>(xyz, cellid, rank, offs, spos);
    knn_kernel<<<dim3(NTOT / 4), 256, 0, stream>>>(spos, cnt, offs, knn, spat);
    transpose_k<<<dim3(NPTS / 32, 128 / 32, NB), dim3(32, 8), 0, stream>>>(x, xT);
    md_k<<<dim3(NPTS / 8, NB), 256, 0, stream>>>(xT, knn, md);
    prep_k<<<1, 128, 0, stream>>>(bb1, bn1g, bn1b, bn1m, bn1v,
                                  bb2, bn2g, bn2b, bn2m, bn2v,
                                  sb1, sbng, sbnb, sbnm, sbnv,
                                  sb2,
                                  ab1, abng, abnb, abnm, abnv,
                                  ab2, sc);
    // spatial MLP: 4->32 (bn,relu), 32->64
    conv_bn<32, 4, 128, 4, 1><<<dim3(NPTS / 128, 1, NB), 256, 0, stream>>>(
        spat, spat, sw1, sc + 512, sc + 544, s1b, nullptr, nullptr, nullptr);
    conv_bn<64, 32, 64, 32, 0><<<dim3(NPTS / 64, 1, NB), 256, 0, stream>>>(
        s1b, s1b, sw2, sc + 576, sc + 640, sfb, nullptr, nullptr, nullptr);
    // boundary net: [x;md] 256->128 (bn,relu), 128->128 (bn,relu)
    conv_bn<128, 256, 32, 128, 1><<<dim3(NPTS / 32, 1, NB), 256, 0, stream>>>(
        x, md, bw1, sc + 0, sc + 128, y1b, nullptr, nullptr, nullptr);
    conv_bn<128, 128, 32, 128, 1><<<dim3(NPTS / 32, 1, NB), 256, 0, stream>>>(
        y1b, y1b, bw2, sc + 256, sc + 384, y2b, nullptr, nullptr, nullptr);
    // attention: [x;sfeat] 192->64 (bn,relu), 64->128 sigmoid + final fuse
    conv_bn<64, 192, 64, 128, 1><<<dim3(NPTS / 64, 1, NB), 256, 0, stream>>>(
        x, sfb, aw1, sc + 704, sc + 768, a1b, nullptr, nullptr, nullptr);
    conv_bn<128, 64, 32, 64, 2><<<dim3(NPTS / 32, 1, NB), 256, 0, stream>>>(
        a1b, a1b, aw2, sc + 832, sc + 960, dout, x, y2b, dout);
}